// Round 1
// baseline (1658.142 us; speedup 1.0000x reference)
//
#include <hip/hip_runtime.h>
#include <cstddef>
#include <cstdint>

#define B_   128
#define L_   31
#define D_   1024
#define DI_  2048
#define DS_  16
#define DC_  5
#define DTR_ 64
#define ROWS (B_ * L_)   // 3968

__device__ __forceinline__ float silu_f(float x) { return x / (1.0f + __expf(-x)); }

// ---------------- LayerNorm (one block per row, D=1024) ----------------
__global__ __launch_bounds__(256) void ln_kernel(const float* __restrict__ x,
                                                 const float* __restrict__ w,
                                                 const float* __restrict__ b,
                                                 float* __restrict__ y)
{
    const int row = blockIdx.x;
    const float* xr = x + (size_t)row * D_;
    float v[4];
    float sum = 0.f, sq = 0.f;
#pragma unroll
    for (int i = 0; i < 4; i++) {
        v[i] = xr[threadIdx.x + i * 256];
        sum += v[i];
        sq  += v[i] * v[i];
    }
#pragma unroll
    for (int o = 32; o > 0; o >>= 1) {
        sum += __shfl_down(sum, o, 64);
        sq  += __shfl_down(sq, o, 64);
    }
    __shared__ float red[8];
    const int wid = threadIdx.x >> 6;
    if ((threadIdx.x & 63) == 0) { red[wid] = sum; red[4 + wid] = sq; }
    __syncthreads();
    sum = red[0] + red[1] + red[2] + red[3];
    sq  = red[4] + red[5] + red[6] + red[7];
    const float mean = sum * (1.0f / D_);
    const float var  = sq * (1.0f / D_) - mean * mean;
    const float rstd = rsqrtf(var + 1e-5f);
    float* yr = y + (size_t)row * D_;
#pragma unroll
    for (int i = 0; i < 4; i++) {
        const int c = threadIdx.x + i * 256;
        yr[c] = (v[i] - mean) * rstd * w[c] + b[c];
    }
}

// ---------------- generic fp32 GEMM: C[M,N] = A[M,K] * W[N,K]^T ----------------
// ACT: 0 none, 1 silu, 2 softplus   applied after bias, before residual
template <int ACT, bool BIAS, bool RES>
__global__ __launch_bounds__(256) void gemm_f32(const float* __restrict__ A, int lda,
                                                const float* __restrict__ W,
                                                const float* __restrict__ bias,
                                                const float* __restrict__ res,
                                                float* __restrict__ C,
                                                int M, int N, int K)
{
    const int bm = blockIdx.y * 64;
    const int bn = blockIdx.x * 64;
    const int tid = threadIdx.x;
    const int tx = tid & 15;
    const int ty = tid >> 4;
    const int lr = tid >> 2;          // 0..63 tile row
    const int lc = (tid & 3) << 2;    // 0,4,8,12 tile col (k)
    __shared__ float As[16][64];
    __shared__ float Ws[16][64];
    float acc[4][4] = {};
    const int am = bm + lr;
    const int wn = bn + lr;

    for (int k0 = 0; k0 < K; k0 += 16) {
        float4 av = make_float4(0.f, 0.f, 0.f, 0.f);
        float4 wv = make_float4(0.f, 0.f, 0.f, 0.f);
        if (am < M) av = *(const float4*)(A + (size_t)am * lda + k0 + lc);
        if (wn < N) wv = *(const float4*)(W + (size_t)wn * K + k0 + lc);
        __syncthreads();
        As[lc + 0][lr] = av.x; As[lc + 1][lr] = av.y; As[lc + 2][lr] = av.z; As[lc + 3][lr] = av.w;
        Ws[lc + 0][lr] = wv.x; Ws[lc + 1][lr] = wv.y; Ws[lc + 2][lr] = wv.z; Ws[lc + 3][lr] = wv.w;
        __syncthreads();
#pragma unroll
        for (int k = 0; k < 16; k++) {
            float a[4], w[4];
#pragma unroll
            for (int i = 0; i < 4; i++) a[i] = As[k][ty * 4 + i];
#pragma unroll
            for (int j = 0; j < 4; j++) w[j] = Ws[k][tx * 4 + j];
#pragma unroll
            for (int i = 0; i < 4; i++)
#pragma unroll
                for (int j = 0; j < 4; j++)
                    acc[i][j] = fmaf(a[i], w[j], acc[i][j]);
        }
    }

#pragma unroll
    for (int i = 0; i < 4; i++) {
        const int m = bm + ty * 4 + i;
        if (m >= M) continue;
#pragma unroll
        for (int j = 0; j < 4; j++) {
            const int n = bn + tx * 4 + j;
            if (n >= N) continue;
            float v = acc[i][j];
            if (BIAS) v += bias[n];
            if (ACT == 1) v = silu_f(v);
            if (ACT == 2) v = (v > 20.0f) ? v : log1pf(__expf(v));
            if (RES) v += res[(size_t)m * N + n];
            C[(size_t)m * N + n] = v;
        }
    }
}

// split-K variant with atomic accumulation (classifier layer 1)
__global__ __launch_bounds__(256) void gemm_f32_atomic(const float* __restrict__ A, int lda,
                                                       const float* __restrict__ W,
                                                       float* __restrict__ C,
                                                       int M, int N, int Ktot, int kLen)
{
    const int bm = blockIdx.y * 64;
    const int bn = blockIdx.x * 64;
    const int kStart = blockIdx.z * kLen;
    const int tid = threadIdx.x;
    const int tx = tid & 15;
    const int ty = tid >> 4;
    const int lr = tid >> 2;
    const int lc = (tid & 3) << 2;
    __shared__ float As[16][64];
    __shared__ float Ws[16][64];
    float acc[4][4] = {};
    const int am = bm + lr;
    const int wn = bn + lr;

    for (int k0 = kStart; k0 < kStart + kLen; k0 += 16) {
        float4 av = make_float4(0.f, 0.f, 0.f, 0.f);
        float4 wv = make_float4(0.f, 0.f, 0.f, 0.f);
        if (am < M) av = *(const float4*)(A + (size_t)am * lda + k0 + lc);
        if (wn < N) wv = *(const float4*)(W + (size_t)wn * Ktot + k0 + lc);
        __syncthreads();
        As[lc + 0][lr] = av.x; As[lc + 1][lr] = av.y; As[lc + 2][lr] = av.z; As[lc + 3][lr] = av.w;
        Ws[lc + 0][lr] = wv.x; Ws[lc + 1][lr] = wv.y; Ws[lc + 2][lr] = wv.z; Ws[lc + 3][lr] = wv.w;
        __syncthreads();
#pragma unroll
        for (int k = 0; k < 16; k++) {
            float a[4], w[4];
#pragma unroll
            for (int i = 0; i < 4; i++) a[i] = As[k][ty * 4 + i];
#pragma unroll
            for (int j = 0; j < 4; j++) w[j] = Ws[k][tx * 4 + j];
#pragma unroll
            for (int i = 0; i < 4; i++)
#pragma unroll
                for (int j = 0; j < 4; j++)
                    acc[i][j] = fmaf(a[i], w[j], acc[i][j]);
        }
    }

#pragma unroll
    for (int i = 0; i < 4; i++) {
        const int m = bm + ty * 4 + i;
        if (m >= M) continue;
#pragma unroll
        for (int j = 0; j < 4; j++) {
            const int n = bn + tx * 4 + j;
            if (n >= N) continue;
            atomicAdd(&C[(size_t)m * N + n], acc[i][j]);
        }
    }
}

// ---------------- causal depthwise conv1d (DC=5) + SiLU ----------------
// u = xz[:, :, 0:DI], laid out per row with stride 2*DI
__global__ __launch_bounds__(256) void conv_silu_kernel(const float* __restrict__ xz,
                                                        const float* __restrict__ cw,
                                                        const float* __restrict__ cb,
                                                        float* __restrict__ uc)
{
    const int idx = blockIdx.x * 256 + threadIdx.x;   // over B*L*DI
    const int d  = idx & (DI_ - 1);
    const int bl = idx >> 11;                         // DI_=2048
    const int l  = bl % L_;
    const int b  = bl / L_;
    const float* u = xz + (size_t)b * L_ * (2 * DI_) + d;
    float acc = cb[d];
#pragma unroll
    for (int k = 0; k < DC_; k++) {
        const int ll = l + k - (DC_ - 1);
        if (ll >= 0) acc = fmaf(u[(size_t)ll * (2 * DI_)], cw[d * DC_ + k], acc);
    }
    uc[(size_t)bl * DI_ + d] = silu_f(acc);
}

// ---------------- selective scan: one thread per (b, d), DS=16 states in regs ----------------
// y buffer may alias dt (same thread reads dt[bl,d] then writes y[bl,d])
__global__ __launch_bounds__(256) void scan_kernel(const float* __restrict__ dt,
                                                   const float* __restrict__ uc,
                                                   const float* __restrict__ xz,
                                                   const float* __restrict__ xdbl,
                                                   const float* __restrict__ A_log,
                                                   const float* __restrict__ D_ssm,
                                                   float* __restrict__ y)
{
    const int idx = blockIdx.x * 256 + threadIdx.x;   // over B*DI
    const int d = idx & (DI_ - 1);
    const int b = idx >> 11;
    float A[DS_];
#pragma unroll
    for (int s = 0; s < DS_; s++) A[s] = -__expf(A_log[d * DS_ + s]);
    const float Dv = D_ssm[d];
    float h[DS_] = {};
    for (int l = 0; l < L_; l++) {
        const size_t bl = (size_t)b * L_ + l;
        const float dtv = dt[bl * DI_ + d];
        const float uv  = uc[bl * DI_ + d];
        const float zv  = xz[bl * (2 * DI_) + DI_ + d];
        const float* Bp = xdbl + bl * (DTR_ + 2 * DS_) + DTR_;
        const float* Cp = Bp + DS_;
        float yv = 0.f;
#pragma unroll
        for (int s = 0; s < DS_; s++) {
            h[s] = fmaf(h[s], __expf(dtv * A[s]), dtv * Bp[s] * uv);
            yv = fmaf(h[s], Cp[s], yv);
        }
        yv = fmaf(uv, Dv, yv);
        yv *= silu_f(zv);
        y[bl * DI_ + d] = yv;
    }
}

// ---------------- classifier layer 2: out[b] = b2 + sum_n silu(c[b,n]+b1[n]) * W2[n] ----------------
__global__ __launch_bounds__(256) void cls2_kernel(const float* __restrict__ c,
                                                   const float* __restrict__ b1,
                                                   const float* __restrict__ W2,
                                                   const float* __restrict__ b2,
                                                   float* __restrict__ out)
{
    const int b = blockIdx.x;
    float s = 0.f;
    for (int n = threadIdx.x; n < D_; n += 256) {
        float v = c[b * D_ + n] + b1[n];
        v = silu_f(v);
        s = fmaf(v, W2[n], s);
    }
#pragma unroll
    for (int o = 32; o > 0; o >>= 1) s += __shfl_down(s, o, 64);
    __shared__ float red[4];
    const int wid = threadIdx.x >> 6;
    if ((threadIdx.x & 63) == 0) red[wid] = s;
    __syncthreads();
    if (threadIdx.x == 0) out[b] = red[0] + red[1] + red[2] + red[3] + b2[0];
}

extern "C" void kernel_launch(void* const* d_in, const int* in_sizes, int n_in,
                              void* d_out, int out_size, void* d_ws, size_t ws_size,
                              hipStream_t stream)
{
    const float* x         = (const float*)d_in[0];
    const float* n1w       = (const float*)d_in[1];
    const float* n1b       = (const float*)d_in[2];
    const float* in_projW  = (const float*)d_in[3];
    const float* conv_w    = (const float*)d_in[4];
    const float* conv_b    = (const float*)d_in[5];
    const float* x_projW   = (const float*)d_in[6];
    const float* dt_projW  = (const float*)d_in[7];
    const float* dt_projb  = (const float*)d_in[8];
    const float* A_log     = (const float*)d_in[9];
    const float* D_ssm     = (const float*)d_in[10];
    const float* out_projW = (const float*)d_in[11];
    const float* n2w       = (const float*)d_in[12];
    const float* n2b       = (const float*)d_in[13];
    const float* ffn_W1    = (const float*)d_in[14];
    const float* ffn_b1    = (const float*)d_in[15];
    const float* ffn_W2    = (const float*)d_in[16];
    const float* ffn_b2    = (const float*)d_in[17];
    const float* cls_W1    = (const float*)d_in[18];
    const float* cls_b1    = (const float*)d_in[19];
    const float* cls_W2    = (const float*)d_in[20];
    const float* cls_b2    = (const float*)d_in[21];

    float* ws   = (float*)d_ws;
    float* xz   = ws;                           // ROWS*4096
    float* uc   = xz + (size_t)ROWS * 4096;     // ROWS*2048  (later reused as ffn hidden)
    float* dty  = uc + (size_t)ROWS * 2048;     // ROWS*2048  (dt, then y in place)
    float* hbuf = dty + (size_t)ROWS * 2048;    // ROWS*1024  (h1, then h2)
    float* x2   = hbuf + (size_t)ROWS * 1024;   // ROWS*1024
    float* xdbl = x2 + (size_t)ROWS * 1024;     // ROWS*96    (later reused as cls hidden 128*1024)

    float* outv = (float*)d_out;    // (B,1) = 128 floats
    float* x3   = outv + B_;        // (B,L,D) = ROWS*1024 floats

    // 1. LN1
    ln_kernel<<<dim3(ROWS), dim3(256), 0, stream>>>(x, n1w, n1b, hbuf);
    // 2. in_proj: xz = h1 @ in_proj_W^T   (3968 x 4096, K=1024)
    gemm_f32<0, false, false><<<dim3(4096 / 64, ROWS / 64), dim3(256), 0, stream>>>(
        hbuf, D_, in_projW, nullptr, nullptr, xz, ROWS, 2 * DI_, D_);
    // 3. causal conv + SiLU
    conv_silu_kernel<<<dim3(ROWS * DI_ / 256), dim3(256), 0, stream>>>(xz, conv_w, conv_b, uc);
    // 4. x_proj: xdbl = uc @ x_proj_W^T   (3968 x 96, K=2048)
    gemm_f32<0, false, false><<<dim3(2, ROWS / 64), dim3(256), 0, stream>>>(
        uc, DI_, x_projW, nullptr, nullptr, xdbl, ROWS, DTR_ + 2 * DS_, DI_);
    // 5. dt_proj + softplus: dt = softplus(xdbl[:, :64] @ dt_proj_W^T + b)  (3968 x 2048, K=64)
    gemm_f32<2, true, false><<<dim3(2048 / 64, ROWS / 64), dim3(256), 0, stream>>>(
        xdbl, DTR_ + 2 * DS_, dt_projW, dt_projb, nullptr, dty, ROWS, DI_, DTR_);
    // 6. selective scan (+ skip term + gate); y overwrites dt in place
    scan_kernel<<<dim3(B_ * DI_ / 256), dim3(256), 0, stream>>>(
        dty, uc, xz, xdbl, A_log, D_ssm, dty);
    // 7. out_proj + residual: x2 = x + y @ out_proj_W^T   (3968 x 1024, K=2048)
    gemm_f32<0, false, true><<<dim3(1024 / 64, ROWS / 64), dim3(256), 0, stream>>>(
        dty, DI_, out_projW, nullptr, x, x2, ROWS, D_, DI_);
    // 8. LN2
    ln_kernel<<<dim3(ROWS), dim3(256), 0, stream>>>(x2, n2w, n2b, hbuf);
    // 9. ffn1 + bias + SiLU: f1 = silu(h2 @ ffn_W1^T + b1)   (3968 x 2048, K=1024) -> reuse uc
    gemm_f32<1, true, false><<<dim3(2048 / 64, ROWS / 64), dim3(256), 0, stream>>>(
        hbuf, D_, ffn_W1, ffn_b1, nullptr, uc, ROWS, 2 * D_, D_);
    // 10. ffn2 + bias + residual: x3 = x2 + f1 @ ffn_W2^T + b2   (3968 x 1024, K=2048) -> d_out
    gemm_f32<0, true, true><<<dim3(1024 / 64, ROWS / 64), dim3(256), 0, stream>>>(
        uc, 2 * D_, ffn_W2, ffn_b2, x2, x3, ROWS, D_, 2 * D_);
    // 11. classifier layer 1 (split-K atomic): c = flat @ cls_W1^T   (128 x 1024, K=31744)
    hipMemsetAsync(xdbl, 0, (size_t)B_ * D_ * sizeof(float), stream);
    gemm_f32_atomic<<<dim3(1024 / 64, 2, 31), dim3(256), 0, stream>>>(
        x3, L_ * D_, cls_W1, xdbl, B_, D_, L_ * D_, 1024);
    // 12. classifier layer 2 (bias+SiLU fused here)
    cls2_kernel<<<dim3(B_), dim3(256), 0, stream>>>(xdbl, cls_b1, cls_W2, cls_b2, outv);
}

// Round 2
// 566.995 us; speedup vs baseline: 2.9244x; 2.9244x over previous
//
#include <hip/hip_runtime.h>
#include <cstddef>
#include <cstdint>

#define B_   128
#define L_   31
#define D_   1024
#define DI_  2048
#define DS_  16
#define DC_  5
#define DTR_ 64
#define ROWS (B_ * L_)   // 3968

typedef unsigned short u16;
typedef __attribute__((ext_vector_type(8))) short s16x8;
typedef __attribute__((ext_vector_type(4))) float f32x4;

__device__ __forceinline__ float silu_f(float x) { return x / (1.0f + __expf(-x)); }

__device__ __forceinline__ u16 f2b(float f) {
    union { float f; uint32_t u; } c; c.f = f;
    uint32_t u = c.u + 0x7FFF + ((c.u >> 16) & 1);
    return (u16)(u >> 16);
}
__device__ __forceinline__ float b2f(u16 b) {
    union { uint32_t u; float f; } c; c.u = ((uint32_t)b) << 16;
    return c.f;
}

#define GLD16(g, s) __builtin_amdgcn_global_load_lds( \
    (const __attribute__((address_space(1))) void*)(g), \
    (__attribute__((address_space(3))) void*)(s), 16, 0, 0)

// ---------------- fp32 -> bf16 converter (8 elems / thread) ----------------
__global__ __launch_bounds__(256) void f2b_kernel(const float* __restrict__ in,
                                                  u16* __restrict__ out, int n8)
{
    int i = blockIdx.x * 256 + threadIdx.x;
    if (i >= n8) return;
    const float4* p = (const float4*)in + (size_t)i * 2;
    float4 a = p[0], b = p[1];
    uint4 r;
    r.x = (uint32_t)f2b(a.x) | ((uint32_t)f2b(a.y) << 16);
    r.y = (uint32_t)f2b(a.z) | ((uint32_t)f2b(a.w) << 16);
    r.z = (uint32_t)f2b(b.x) | ((uint32_t)f2b(b.y) << 16);
    r.w = (uint32_t)f2b(b.z) | ((uint32_t)f2b(b.w) << 16);
    ((uint4*)out)[i] = r;
}

// ---------------- LayerNorm (one block per row, D=1024) -> bf16 out ----------------
__global__ __launch_bounds__(256) void ln_kernel(const float* __restrict__ x,
                                                 const float* __restrict__ w,
                                                 const float* __restrict__ b,
                                                 u16* __restrict__ y)
{
    const int row = blockIdx.x;
    const float* xr = x + (size_t)row * D_;
    float v[4];
    float sum = 0.f, sq = 0.f;
#pragma unroll
    for (int i = 0; i < 4; i++) {
        v[i] = xr[threadIdx.x + i * 256];
        sum += v[i];
        sq  += v[i] * v[i];
    }
#pragma unroll
    for (int o = 32; o > 0; o >>= 1) {
        sum += __shfl_down(sum, o, 64);
        sq  += __shfl_down(sq, o, 64);
    }
    __shared__ float red[8];
    const int wid = threadIdx.x >> 6;
    if ((threadIdx.x & 63) == 0) { red[wid] = sum; red[4 + wid] = sq; }
    __syncthreads();
    sum = red[0] + red[1] + red[2] + red[3];
    sq  = red[4] + red[5] + red[6] + red[7];
    const float mean = sum * (1.0f / D_);
    const float var  = sq * (1.0f / D_) - mean * mean;
    const float rstd = rsqrtf(var + 1e-5f);
    u16* yr = y + (size_t)row * D_;
#pragma unroll
    for (int i = 0; i < 4; i++) {
        const int c = threadIdx.x + i * 256;
        yr[c] = f2b((v[i] - mean) * rstd * w[c] + b[c]);
    }
}

// ---------------- bf16 MFMA GEMM: C[M,Nout] = A[M,K] @ W[Npad,K]^T ----------------
// m97 structure: 128x128 tile, BK=32, 4 waves (2x2), global_load_lds width 16,
// 16x16x32 MFMA, C/D layout col=lane&15, row=(lane>>4)*4+reg (m89-verified).
// ACT: 0 none, 1 silu. BIAS/RES read f32. OUTB: write bf16 else f32.
template <int ACT, bool BIAS, bool RES, bool OUTB>
__global__ __launch_bounds__(256) void gemm_mfma(
    const u16* __restrict__ A, const u16* __restrict__ W,
    const float* __restrict__ bias, const float* __restrict__ res,
    void* __restrict__ Cout, int M, int K, int Nout)
{
    __shared__ __align__(16) u16 As[128 * 32];
    __shared__ __align__(16) u16 Bs[128 * 32];
    const int tid = threadIdx.x;
    const int l = tid & 63, w = tid >> 6;
    const int bm = blockIdx.y * 128, bn = blockIdx.x * 128;

    // staging: wave w covers 1KB chunks w and w+4 of each 8KB tile (linear LDS)
    const int sr = l >> 2;           // 0..15 row within 16-row chunk
    const int sk = (l & 3) * 8;      // k-element offset (16B granules)
    const u16* gA = A + (size_t)(bm + w * 16 + sr) * K + sk;
    const u16* gB = W + (size_t)(bn + w * 16 + sr) * K + sk;
    u16* lA = As + (w * 16 + sr) * 32 + sk;   // == As + w*1024B/2 + l*16B/2
    u16* lB = Bs + (w * 16 + sr) * 32 + sk;

    // fragment read addresses
    const int lane15 = l & 15, lhi = l >> 4;
    const int wr = w >> 1, wc = w & 1;
    const u16* fA = As + (wr * 64 + lane15) * 32 + lhi * 8;
    const u16* fB = Bs + (wc * 64 + lane15) * 32 + lhi * 8;

    f32x4 acc[4][4] = {};

    for (int k0 = 0; k0 < K; k0 += 32) {
        GLD16(gA, lA); GLD16(gA + (size_t)64 * K, lA + 64 * 32);
        GLD16(gB, lB); GLD16(gB + (size_t)64 * K, lB + 64 * 32);
        gA += 32; gB += 32;
        __syncthreads();                       // vmcnt(0) drain -> tiles ready
        s16x8 af[4], bfr[4];
#pragma unroll
        for (int mi = 0; mi < 4; mi++) af[mi]  = *(const s16x8*)(fA + mi * 16 * 32);
#pragma unroll
        for (int ni = 0; ni < 4; ni++) bfr[ni] = *(const s16x8*)(fB + ni * 16 * 32);
#pragma unroll
        for (int mi = 0; mi < 4; mi++)
#pragma unroll
            for (int ni = 0; ni < 4; ni++)
                acc[mi][ni] = __builtin_amdgcn_mfma_f32_16x16x32_bf16(
                    af[mi], bfr[ni], acc[mi][ni], 0, 0, 0);
        __syncthreads();                       // reads done before next stage
    }

#pragma unroll
    for (int ni = 0; ni < 4; ni++) {
        const int col = bn + wc * 64 + ni * 16 + lane15;
        if (col >= Nout) continue;
        const float bv = BIAS ? bias[col] : 0.0f;
#pragma unroll
        for (int mi = 0; mi < 4; mi++) {
#pragma unroll
            for (int r = 0; r < 4; r++) {
                const int row = bm + wr * 64 + mi * 16 + lhi * 4 + r;
                float v = acc[mi][ni][r] + bv;
                if (ACT == 1) v = silu_f(v);
                if (RES) v += res[(size_t)row * Nout + col];
                if (OUTB) ((u16*)Cout)[(size_t)row * Nout + col] = f2b(v);
                else      ((float*)Cout)[(size_t)row * Nout + col] = v;
            }
        }
    }
}

// ---------------- fp32 GEMM (dt_proj only): C = softplus(A @ W^T + b) -> bf16 ----------------
template <int ACT, bool BIAS, bool OUTB>
__global__ __launch_bounds__(256) void gemm_f32(const float* __restrict__ A, int lda,
                                                const float* __restrict__ W,
                                                const float* __restrict__ bias,
                                                void* __restrict__ C,
                                                int M, int N, int K)
{
    const int bm = blockIdx.y * 64;
    const int bn = blockIdx.x * 64;
    const int tid = threadIdx.x;
    const int tx = tid & 15;
    const int ty = tid >> 4;
    const int lr = tid >> 2;
    const int lc = (tid & 3) << 2;
    __shared__ float As[16][64];
    __shared__ float Ws[16][64];
    float acc[4][4] = {};
    const int am = bm + lr;
    const int wn = bn + lr;

    for (int k0 = 0; k0 < K; k0 += 16) {
        float4 av = make_float4(0.f, 0.f, 0.f, 0.f);
        float4 wv = make_float4(0.f, 0.f, 0.f, 0.f);
        if (am < M) av = *(const float4*)(A + (size_t)am * lda + k0 + lc);
        if (wn < N) wv = *(const float4*)(W + (size_t)wn * K + k0 + lc);
        __syncthreads();
        As[lc + 0][lr] = av.x; As[lc + 1][lr] = av.y; As[lc + 2][lr] = av.z; As[lc + 3][lr] = av.w;
        Ws[lc + 0][lr] = wv.x; Ws[lc + 1][lr] = wv.y; Ws[lc + 2][lr] = wv.z; Ws[lc + 3][lr] = wv.w;
        __syncthreads();
#pragma unroll
        for (int k = 0; k < 16; k++) {
            float a[4], wv2[4];
#pragma unroll
            for (int i = 0; i < 4; i++) a[i] = As[k][ty * 4 + i];
#pragma unroll
            for (int j = 0; j < 4; j++) wv2[j] = Ws[k][tx * 4 + j];
#pragma unroll
            for (int i = 0; i < 4; i++)
#pragma unroll
                for (int j = 0; j < 4; j++)
                    acc[i][j] = fmaf(a[i], wv2[j], acc[i][j]);
        }
    }

#pragma unroll
    for (int i = 0; i < 4; i++) {
        const int m = bm + ty * 4 + i;
        if (m >= M) continue;
#pragma unroll
        for (int j = 0; j < 4; j++) {
            const int n = bn + tx * 4 + j;
            if (n >= N) continue;
            float v = acc[i][j];
            if (BIAS) v += bias[n];
            if (ACT == 2) v = (v > 20.0f) ? v : log1pf(__expf(v));
            if (OUTB) ((u16*)C)[(size_t)m * N + n] = f2b(v);
            else      ((float*)C)[(size_t)m * N + n] = v;
        }
    }
}

// split-K fp32 GEMM with atomic accumulation (classifier layer 1)
__global__ __launch_bounds__(256) void gemm_f32_atomic(const float* __restrict__ A, int lda,
                                                       const float* __restrict__ W,
                                                       float* __restrict__ C,
                                                       int M, int N, int Ktot, int kLen)
{
    const int bm = blockIdx.y * 64;
    const int bn = blockIdx.x * 64;
    const int kStart = blockIdx.z * kLen;
    const int tid = threadIdx.x;
    const int tx = tid & 15;
    const int ty = tid >> 4;
    const int lr = tid >> 2;
    const int lc = (tid & 3) << 2;
    __shared__ float As[16][64];
    __shared__ float Ws[16][64];
    float acc[4][4] = {};
    const int am = bm + lr;
    const int wn = bn + lr;

    for (int k0 = kStart; k0 < kStart + kLen; k0 += 16) {
        float4 av = make_float4(0.f, 0.f, 0.f, 0.f);
        float4 wv = make_float4(0.f, 0.f, 0.f, 0.f);
        if (am < M) av = *(const float4*)(A + (size_t)am * lda + k0 + lc);
        if (wn < N) wv = *(const float4*)(W + (size_t)wn * Ktot + k0 + lc);
        __syncthreads();
        As[lc + 0][lr] = av.x; As[lc + 1][lr] = av.y; As[lc + 2][lr] = av.z; As[lc + 3][lr] = av.w;
        Ws[lc + 0][lr] = wv.x; Ws[lc + 1][lr] = wv.y; Ws[lc + 2][lr] = wv.z; Ws[lc + 3][lr] = wv.w;
        __syncthreads();
#pragma unroll
        for (int k = 0; k < 16; k++) {
            float a[4], wv2[4];
#pragma unroll
            for (int i = 0; i < 4; i++) a[i] = As[k][ty * 4 + i];
#pragma unroll
            for (int j = 0; j < 4; j++) wv2[j] = Ws[k][tx * 4 + j];
#pragma unroll
            for (int i = 0; i < 4; i++)
#pragma unroll
                for (int j = 0; j < 4; j++)
                    acc[i][j] = fmaf(a[i], wv2[j], acc[i][j]);
        }
    }

#pragma unroll
    for (int i = 0; i < 4; i++) {
        const int m = bm + ty * 4 + i;
        if (m >= M) continue;
#pragma unroll
        for (int j = 0; j < 4; j++) {
            const int n = bn + tx * 4 + j;
            if (n >= N) continue;
            atomicAdd(&C[(size_t)m * N + n], acc[i][j]);
        }
    }
}

// ---------------- causal depthwise conv1d (DC=5) + SiLU -> bf16 ----------------
__global__ __launch_bounds__(256) void conv_silu_kernel(const float* __restrict__ xz,
                                                        const float* __restrict__ cw,
                                                        const float* __restrict__ cb,
                                                        u16* __restrict__ uc)
{
    const int idx = blockIdx.x * 256 + threadIdx.x;   // over B*L*DI
    const int d  = idx & (DI_ - 1);
    const int bl = idx >> 11;
    const int l  = bl % L_;
    const int b  = bl / L_;
    const float* u = xz + (size_t)b * L_ * (2 * DI_) + d;
    float acc = cb[d];
#pragma unroll
    for (int k = 0; k < DC_; k++) {
        const int ll = l + k - (DC_ - 1);
        if (ll >= 0) acc = fmaf(u[(size_t)ll * (2 * DI_)], cw[d * DC_ + k], acc);
    }
    uc[(size_t)bl * DI_ + d] = f2b(silu_f(acc));
}

// ---------------- selective scan: one thread per (b, d), DS=16 states in regs ----------------
__global__ __launch_bounds__(256) void scan_kernel(const u16* __restrict__ dt,
                                                   const u16* __restrict__ uc,
                                                   const float* __restrict__ xz,
                                                   const float* __restrict__ xdbl,
                                                   const float* __restrict__ A_log,
                                                   const float* __restrict__ D_ssm,
                                                   u16* __restrict__ y)
{
    const int idx = blockIdx.x * 256 + threadIdx.x;   // over B*DI
    const int d = idx & (DI_ - 1);
    const int b = idx >> 11;
    float A[DS_];
#pragma unroll
    for (int s = 0; s < DS_; s++) A[s] = -__expf(A_log[d * DS_ + s]);
    const float Dv = D_ssm[d];
    float h[DS_] = {};
    for (int l = 0; l < L_; l++) {
        const size_t bl = (size_t)b * L_ + l;
        const float dtv = b2f(dt[bl * DI_ + d]);
        const float uv  = b2f(uc[bl * DI_ + d]);
        const float zv  = xz[bl * (2 * DI_) + DI_ + d];
        const float* Bp = xdbl + bl * (DTR_ + 2 * DS_) + DTR_;
        const float* Cp = Bp + DS_;
        float yv = 0.f;
#pragma unroll
        for (int s = 0; s < DS_; s++) {
            h[s] = fmaf(h[s], __expf(dtv * A[s]), dtv * Bp[s] * uv);
            yv = fmaf(h[s], Cp[s], yv);
        }
        yv = fmaf(uv, Dv, yv);
        yv *= silu_f(zv);
        y[bl * DI_ + d] = f2b(yv);
    }
}

// ---------------- classifier layer 2 ----------------
__global__ __launch_bounds__(256) void cls2_kernel(const float* __restrict__ c,
                                                   const float* __restrict__ b1,
                                                   const float* __restrict__ W2,
                                                   const float* __restrict__ b2,
                                                   float* __restrict__ out)
{
    const int b = blockIdx.x;
    float s = 0.f;
    for (int n = threadIdx.x; n < D_; n += 256) {
        float v = c[b * D_ + n] + b1[n];
        v = silu_f(v);
        s = fmaf(v, W2[n], s);
    }
#pragma unroll
    for (int o = 32; o > 0; o >>= 1) s += __shfl_down(s, o, 64);
    __shared__ float red[4];
    const int wid = threadIdx.x >> 6;
    if ((threadIdx.x & 63) == 0) red[wid] = s;
    __syncthreads();
    if (threadIdx.x == 0) out[b] = red[0] + red[1] + red[2] + red[3] + b2[0];
}

extern "C" void kernel_launch(void* const* d_in, const int* in_sizes, int n_in,
                              void* d_out, int out_size, void* d_ws, size_t ws_size,
                              hipStream_t stream)
{
    const float* x         = (const float*)d_in[0];
    const float* n1w       = (const float*)d_in[1];
    const float* n1b       = (const float*)d_in[2];
    const float* in_projW  = (const float*)d_in[3];
    const float* conv_w    = (const float*)d_in[4];
    const float* conv_b    = (const float*)d_in[5];
    const float* x_projW   = (const float*)d_in[6];
    const float* dt_projW  = (const float*)d_in[7];
    const float* dt_projb  = (const float*)d_in[8];
    const float* A_log     = (const float*)d_in[9];
    const float* D_ssm     = (const float*)d_in[10];
    const float* out_projW = (const float*)d_in[11];
    const float* n2w       = (const float*)d_in[12];
    const float* n2b       = (const float*)d_in[13];
    const float* ffn_W1    = (const float*)d_in[14];
    const float* ffn_b1    = (const float*)d_in[15];
    const float* ffn_W2    = (const float*)d_in[16];
    const float* ffn_b2    = (const float*)d_in[17];
    const float* cls_W1    = (const float*)d_in[18];
    const float* cls_b1    = (const float*)d_in[19];
    const float* cls_W2    = (const float*)d_in[20];
    const float* cls_b2    = (const float*)d_in[21];

    // ---- workspace layout (floats; ~149 MB total) ----
    float* ws   = (float*)d_ws;
    float* xz   = ws;                              // ROWS*4096 f32
    u16*   uc_b = (u16*)(xz + (size_t)ROWS * 4096);    // ROWS*2048 u16 (uc, later ffn hidden)
    u16*   dt_b = uc_b + (size_t)ROWS * 2048;          // ROWS*2048 u16
    u16*   y_b  = dt_b + (size_t)ROWS * 2048;          // ROWS*2048 u16
    u16*   h_b  = y_b + (size_t)ROWS * 2048;           // ROWS*1024 u16 (ln out)
    float* x2   = (float*)(h_b + (size_t)ROWS * 1024); // ROWS*1024 f32
    float* xdbl = x2 + (size_t)ROWS * 1024;            // ROWS*96 f32
    u16*   wbuf = (u16*)(xdbl + (size_t)ROWS * 96);    // 4096*1024 u16 (shared weight buf)
    float* clsh = (float*)(wbuf + (size_t)4096 * 1024);// 128*1024 f32

    float* outv = (float*)d_out;    // (B,1)
    float* x3   = outv + B_;        // (B,L,D)

    // 1. LN1 -> bf16
    ln_kernel<<<dim3(ROWS), dim3(256), 0, stream>>>(x, n1w, n1b, h_b);
    // 2. in_proj (MFMA): xz = h1 @ in_proj_W^T   (3968 x 4096, K=1024)
    f2b_kernel<<<dim3(4096 * 1024 / 8 / 256), dim3(256), 0, stream>>>(in_projW, wbuf, 4096 * 1024 / 8);
    gemm_mfma<0, false, false, false><<<dim3(4096 / 128, ROWS / 128), dim3(256), 0, stream>>>(
        h_b, wbuf, nullptr, nullptr, xz, ROWS, D_, 2 * DI_);
    // 3. causal conv + SiLU -> bf16
    conv_silu_kernel<<<dim3(ROWS * DI_ / 256), dim3(256), 0, stream>>>(xz, conv_w, conv_b, uc_b);
    // 4. x_proj (MFMA, N padded 96->128): xdbl = uc @ x_proj_W^T   (3968 x 96, K=2048)
    hipMemsetAsync(wbuf, 0, (size_t)128 * 2048 * sizeof(u16), stream);
    f2b_kernel<<<dim3(96 * 2048 / 8 / 256), dim3(256), 0, stream>>>(x_projW, wbuf, 96 * 2048 / 8);
    gemm_mfma<0, false, false, false><<<dim3(1, ROWS / 128), dim3(256), 0, stream>>>(
        uc_b, wbuf, nullptr, nullptr, xdbl, ROWS, DI_, DTR_ + 2 * DS_);
    // 5. dt_proj + softplus -> bf16: dt = softplus(xdbl[:,:64] @ dt_proj_W^T + b)  (3968 x 2048, K=64)
    gemm_f32<2, true, true><<<dim3(2048 / 64, ROWS / 64), dim3(256), 0, stream>>>(
        xdbl, DTR_ + 2 * DS_, dt_projW, dt_projb, dt_b, ROWS, DI_, DTR_);
    // 6. selective scan (+ skip + gate) -> bf16 y
    scan_kernel<<<dim3(B_ * DI_ / 256), dim3(256), 0, stream>>>(
        dt_b, uc_b, xz, xdbl, A_log, D_ssm, y_b);
    // 7. out_proj (MFMA) + residual: x2 = x + y @ out_proj_W^T   (3968 x 1024, K=2048)
    f2b_kernel<<<dim3(1024 * 2048 / 8 / 256), dim3(256), 0, stream>>>(out_projW, wbuf, 1024 * 2048 / 8);
    gemm_mfma<0, false, true, false><<<dim3(1024 / 128, ROWS / 128), dim3(256), 0, stream>>>(
        y_b, wbuf, nullptr, x, x2, ROWS, DI_, D_);
    // 8. LN2 -> bf16
    ln_kernel<<<dim3(ROWS), dim3(256), 0, stream>>>(x2, n2w, n2b, h_b);
    // 9. ffn1 (MFMA) + bias + SiLU -> bf16 (reuse uc_b)   (3968 x 2048, K=1024)
    f2b_kernel<<<dim3(2048 * 1024 / 8 / 256), dim3(256), 0, stream>>>(ffn_W1, wbuf, 2048 * 1024 / 8);
    gemm_mfma<1, true, false, true><<<dim3(2048 / 128, ROWS / 128), dim3(256), 0, stream>>>(
        h_b, wbuf, ffn_b1, nullptr, uc_b, ROWS, D_, 2 * D_);
    // 10. ffn2 (MFMA) + bias + residual -> x3 (d_out)   (3968 x 1024, K=2048)
    f2b_kernel<<<dim3(1024 * 2048 / 8 / 256), dim3(256), 0, stream>>>(ffn_W2, wbuf, 1024 * 2048 / 8);
    gemm_mfma<0, true, true, false><<<dim3(1024 / 128, ROWS / 128), dim3(256), 0, stream>>>(
        uc_b, wbuf, ffn_b2, x2, x3, ROWS, 2 * D_, D_);
    // 11. classifier layer 1 (split-K atomic, fp32/memory-bound): c = flat @ cls_W1^T
    hipMemsetAsync(clsh, 0, (size_t)B_ * D_ * sizeof(float), stream);
    gemm_f32_atomic<<<dim3(1024 / 64, 2, 31), dim3(256), 0, stream>>>(
        x3, L_ * D_, cls_W1, clsh, B_, D_, L_ * D_, 1024);
    // 12. classifier layer 2
    cls2_kernel<<<dim3(B_), dim3(256), 0, stream>>>(clsh, cls_b1, cls_W2, cls_b2, outv);
}

// Round 3
// 473.453 us; speedup vs baseline: 3.5022x; 1.1976x over previous
//
#include <hip/hip_runtime.h>
#include <cstddef>
#include <cstdint>

#define B_   128
#define L_   31
#define D_   1024
#define DI_  2048
#define DS_  16
#define DC_  5
#define DTR_ 64
#define ROWS (B_ * L_)   // 3968
#define KCLS (L_ * D_)   // 31744

typedef unsigned short u16;
typedef __attribute__((ext_vector_type(8))) short s16x8;
typedef __attribute__((ext_vector_type(4))) float f32x4;

__device__ __forceinline__ float silu_f(float x) { return x / (1.0f + __expf(-x)); }

__device__ __forceinline__ u16 f2b(float f) {
    union { float f; uint32_t u; } c; c.f = f;
    uint32_t u = c.u + 0x7FFF + ((c.u >> 16) & 1);
    return (u16)(u >> 16);
}
__device__ __forceinline__ float b2f(u16 b) {
    union { uint32_t u; float f; } c; c.u = ((uint32_t)b) << 16;
    return c.f;
}
__device__ __forceinline__ uint32_t pack2(float lo, float hi) {
    return (uint32_t)f2b(lo) | ((uint32_t)f2b(hi) << 16);
}

#define GLD16(g, s) __builtin_amdgcn_global_load_lds( \
    (const __attribute__((address_space(1))) void*)(g), \
    (__attribute__((address_space(3))) void*)(s), 16, 0, 0)

// ---------------- fp32 -> bf16 converter (8 elems / thread) ----------------
__global__ __launch_bounds__(256) void f2b_kernel(const float* __restrict__ in,
                                                  u16* __restrict__ out, int n8)
{
    int i = blockIdx.x * 256 + threadIdx.x;
    if (i >= n8) return;
    const float4* p = (const float4*)in + (size_t)i * 2;
    float4 a = p[0], b = p[1];
    uint4 r;
    r.x = pack2(a.x, a.y); r.y = pack2(a.z, a.w);
    r.z = pack2(b.x, b.y); r.w = pack2(b.z, b.w);
    ((uint4*)out)[i] = r;
}

// ---------------- LayerNorm (one block per row, D=1024) -> bf16 out ----------------
__global__ __launch_bounds__(256) void ln_kernel(const float* __restrict__ x,
                                                 const float* __restrict__ w,
                                                 const float* __restrict__ b,
                                                 u16* __restrict__ y)
{
    const int row = blockIdx.x;
    const float* xr = x + (size_t)row * D_;
    float v[4];
    float sum = 0.f, sq = 0.f;
#pragma unroll
    for (int i = 0; i < 4; i++) {
        v[i] = xr[threadIdx.x + i * 256];
        sum += v[i];
        sq  += v[i] * v[i];
    }
#pragma unroll
    for (int o = 32; o > 0; o >>= 1) {
        sum += __shfl_down(sum, o, 64);
        sq  += __shfl_down(sq, o, 64);
    }
    __shared__ float red[8];
    const int wid = threadIdx.x >> 6;
    if ((threadIdx.x & 63) == 0) { red[wid] = sum; red[4 + wid] = sq; }
    __syncthreads();
    sum = red[0] + red[1] + red[2] + red[3];
    sq  = red[4] + red[5] + red[6] + red[7];
    const float mean = sum * (1.0f / D_);
    const float var  = sq * (1.0f / D_) - mean * mean;
    const float rstd = rsqrtf(var + 1e-5f);
    u16* yr = y + (size_t)row * D_;
#pragma unroll
    for (int i = 0; i < 4; i++) {
        const int c = threadIdx.x + i * 256;
        yr[c] = f2b((v[i] - mean) * rstd * w[c] + b[c]);
    }
}

// ---------------- bf16 MFMA GEMM: C[M,Nout] = A[M,K] @ W[Npad,K]^T ----------------
// m97 structure: 128x128 tile, BK=32, 4 waves (2x2), global_load_lds width 16,
// 16x16x32 MFMA, C/D layout col=lane&15, row=(lane>>4)*4+reg (m89-verified).
// ACT: 0 none, 1 silu. BIAS/RES read f32. OUTB: write bf16 else f32.
template <int ACT, bool BIAS, bool RES, bool OUTB>
__global__ __launch_bounds__(256) void gemm_mfma(
    const u16* __restrict__ A, const u16* __restrict__ W,
    const float* __restrict__ bias, const float* __restrict__ res,
    void* __restrict__ Cout, int M, int K, int Nout)
{
    __shared__ __align__(16) u16 As[128 * 32];
    __shared__ __align__(16) u16 Bs[128 * 32];
    const int tid = threadIdx.x;
    const int l = tid & 63, w = tid >> 6;
    const int bm = blockIdx.y * 128, bn = blockIdx.x * 128;

    const int sr = l >> 2;           // 0..15 row within 16-row chunk
    const int sk = (l & 3) * 8;      // k-element offset (16B granules)
    const u16* gA = A + (size_t)(bm + w * 16 + sr) * K + sk;
    const u16* gB = W + (size_t)(bn + w * 16 + sr) * K + sk;
    u16* lA = As + (w * 16 + sr) * 32 + sk;
    u16* lB = Bs + (w * 16 + sr) * 32 + sk;

    const int lane15 = l & 15, lhi = l >> 4;
    const int wr = w >> 1, wc = w & 1;
    const u16* fA = As + (wr * 64 + lane15) * 32 + lhi * 8;
    const u16* fB = Bs + (wc * 64 + lane15) * 32 + lhi * 8;

    f32x4 acc[4][4] = {};

    for (int k0 = 0; k0 < K; k0 += 32) {
        GLD16(gA, lA); GLD16(gA + (size_t)64 * K, lA + 64 * 32);
        GLD16(gB, lB); GLD16(gB + (size_t)64 * K, lB + 64 * 32);
        gA += 32; gB += 32;
        __syncthreads();
        s16x8 af[4], bfr[4];
#pragma unroll
        for (int mi = 0; mi < 4; mi++) af[mi]  = *(const s16x8*)(fA + mi * 16 * 32);
#pragma unroll
        for (int ni = 0; ni < 4; ni++) bfr[ni] = *(const s16x8*)(fB + ni * 16 * 32);
#pragma unroll
        for (int mi = 0; mi < 4; mi++)
#pragma unroll
            for (int ni = 0; ni < 4; ni++)
                acc[mi][ni] = __builtin_amdgcn_mfma_f32_16x16x32_bf16(
                    af[mi], bfr[ni], acc[mi][ni], 0, 0, 0);
        __syncthreads();
    }

#pragma unroll
    for (int ni = 0; ni < 4; ni++) {
        const int col = bn + wc * 64 + ni * 16 + lane15;
        if (col >= Nout) continue;
        const float bv = BIAS ? bias[col] : 0.0f;
#pragma unroll
        for (int mi = 0; mi < 4; mi++) {
#pragma unroll
            for (int r = 0; r < 4; r++) {
                const int row = bm + wr * 64 + mi * 16 + lhi * 4 + r;
                float v = acc[mi][ni][r] + bv;
                if (ACT == 1) v = silu_f(v);
                if (RES) v += res[(size_t)row * Nout + col];
                if (OUTB) ((u16*)Cout)[(size_t)row * Nout + col] = f2b(v);
                else      ((float*)Cout)[(size_t)row * Nout + col] = v;
            }
        }
    }
}

// ---------------- classifier layer 1: split-K MFMA with fused f32->bf16 staging ----------------
// C[128,1024] += A[128,31744] @ W[1024,31744]^T over K-chunk of 512 per block.
// Memory-bound on W (130 MB f32, read exactly once). Atomic f32 accumulate.
#define KCH 512
__global__ __launch_bounds__(256) void gemm_cls_mfma(
    const float* __restrict__ A, const float* __restrict__ W,
    float* __restrict__ C)
{
    __shared__ __align__(16) u16 As[128 * 32];
    __shared__ __align__(16) u16 Bs[128 * 32];
    const int tid = threadIdx.x;
    const int l = tid & 63, w = tid >> 6;
    const int bn = blockIdx.x * 128;
    const int k0 = blockIdx.y * KCH;

    const int sr = l >> 2;
    const int sk = (l & 3) * 8;
    const int row = w * 16 + sr;                // 0..63
    const float* gA0 = A + (size_t)row * KCLS + k0 + sk;
    const float* gA1 = gA0 + (size_t)64 * KCLS;
    const float* gB0 = W + (size_t)(bn + row) * KCLS + k0 + sk;
    const float* gB1 = gB0 + (size_t)64 * KCLS;
    u16* lA0 = As + row * 32 + sk;  u16* lA1 = lA0 + 64 * 32;
    u16* lB0 = Bs + row * 32 + sk;  u16* lB1 = lB0 + 64 * 32;

    const int lane15 = l & 15, lhi = l >> 4;
    const int wr = w >> 1, wc = w & 1;
    const u16* fA = As + (wr * 64 + lane15) * 32 + lhi * 8;
    const u16* fB = Bs + (wc * 64 + lane15) * 32 + lhi * 8;

    f32x4 acc[4][4] = {};

    for (int ks = 0; ks < KCH / 32; ks++) {
        float4 a00 = *(const float4*)(gA0);     float4 a01 = *(const float4*)(gA0 + 4);
        float4 a10 = *(const float4*)(gA1);     float4 a11 = *(const float4*)(gA1 + 4);
        float4 b00 = *(const float4*)(gB0);     float4 b01 = *(const float4*)(gB0 + 4);
        float4 b10 = *(const float4*)(gB1);     float4 b11 = *(const float4*)(gB1 + 4);
        gA0 += 32; gA1 += 32; gB0 += 32; gB1 += 32;
        __syncthreads();                        // prev-iter LDS reads done
        uint4 r;
        r.x = pack2(a00.x, a00.y); r.y = pack2(a00.z, a00.w);
        r.z = pack2(a01.x, a01.y); r.w = pack2(a01.z, a01.w);
        *(uint4*)lA0 = r;
        r.x = pack2(a10.x, a10.y); r.y = pack2(a10.z, a10.w);
        r.z = pack2(a11.x, a11.y); r.w = pack2(a11.z, a11.w);
        *(uint4*)lA1 = r;
        r.x = pack2(b00.x, b00.y); r.y = pack2(b00.z, b00.w);
        r.z = pack2(b01.x, b01.y); r.w = pack2(b01.z, b01.w);
        *(uint4*)lB0 = r;
        r.x = pack2(b10.x, b10.y); r.y = pack2(b10.z, b10.w);
        r.z = pack2(b11.x, b11.y); r.w = pack2(b11.z, b11.w);
        *(uint4*)lB1 = r;
        __syncthreads();                        // writes visible
        s16x8 af[4], bfr[4];
#pragma unroll
        for (int mi = 0; mi < 4; mi++) af[mi]  = *(const s16x8*)(fA + mi * 16 * 32);
#pragma unroll
        for (int ni = 0; ni < 4; ni++) bfr[ni] = *(const s16x8*)(fB + ni * 16 * 32);
#pragma unroll
        for (int mi = 0; mi < 4; mi++)
#pragma unroll
            for (int ni = 0; ni < 4; ni++)
                acc[mi][ni] = __builtin_amdgcn_mfma_f32_16x16x32_bf16(
                    af[mi], bfr[ni], acc[mi][ni], 0, 0, 0);
    }

#pragma unroll
    for (int ni = 0; ni < 4; ni++) {
        const int col = bn + wc * 64 + ni * 16 + lane15;
#pragma unroll
        for (int mi = 0; mi < 4; mi++) {
#pragma unroll
            for (int r = 0; r < 4; r++) {
                const int m = wr * 64 + mi * 16 + lhi * 4 + r;
                atomicAdd(&C[(size_t)m * 1024 + col], acc[mi][ni][r]);
            }
        }
    }
}

// ---------------- fp32 GEMM (dt_proj only): C = softplus(A @ W^T + b) -> bf16 ----------------
template <int ACT, bool BIAS, bool OUTB>
__global__ __launch_bounds__(256) void gemm_f32(const float* __restrict__ A, int lda,
                                                const float* __restrict__ W,
                                                const float* __restrict__ bias,
                                                void* __restrict__ C,
                                                int M, int N, int K)
{
    const int bm = blockIdx.y * 64;
    const int bn = blockIdx.x * 64;
    const int tid = threadIdx.x;
    const int tx = tid & 15;
    const int ty = tid >> 4;
    const int lr = tid >> 2;
    const int lc = (tid & 3) << 2;
    __shared__ float As[16][64];
    __shared__ float Ws[16][64];
    float acc[4][4] = {};
    const int am = bm + lr;
    const int wn = bn + lr;

    for (int k0 = 0; k0 < K; k0 += 16) {
        float4 av = make_float4(0.f, 0.f, 0.f, 0.f);
        float4 wv = make_float4(0.f, 0.f, 0.f, 0.f);
        if (am < M) av = *(const float4*)(A + (size_t)am * lda + k0 + lc);
        if (wn < N) wv = *(const float4*)(W + (size_t)wn * K + k0 + lc);
        __syncthreads();
        As[lc + 0][lr] = av.x; As[lc + 1][lr] = av.y; As[lc + 2][lr] = av.z; As[lc + 3][lr] = av.w;
        Ws[lc + 0][lr] = wv.x; Ws[lc + 1][lr] = wv.y; Ws[lc + 2][lr] = wv.z; Ws[lc + 3][lr] = wv.w;
        __syncthreads();
#pragma unroll
        for (int k = 0; k < 16; k++) {
            float a[4], wv2[4];
#pragma unroll
            for (int i = 0; i < 4; i++) a[i] = As[k][ty * 4 + i];
#pragma unroll
            for (int j = 0; j < 4; j++) wv2[j] = Ws[k][tx * 4 + j];
#pragma unroll
            for (int i = 0; i < 4; i++)
#pragma unroll
                for (int j = 0; j < 4; j++)
                    acc[i][j] = fmaf(a[i], wv2[j], acc[i][j]);
        }
    }

#pragma unroll
    for (int i = 0; i < 4; i++) {
        const int m = bm + ty * 4 + i;
        if (m >= M) continue;
#pragma unroll
        for (int j = 0; j < 4; j++) {
            const int n = bn + tx * 4 + j;
            if (n >= N) continue;
            float v = acc[i][j];
            if (BIAS) v += bias[n];
            if (ACT == 2) v = (v > 20.0f) ? v : log1pf(__expf(v));
            if (OUTB) ((u16*)C)[(size_t)m * N + n] = f2b(v);
            else      ((float*)C)[(size_t)m * N + n] = v;
        }
    }
}

// ---------------- causal depthwise conv1d (DC=5) + SiLU -> bf16 (bf16 in) ----------------
__global__ __launch_bounds__(256) void conv_silu_kernel(const u16* __restrict__ xz,
                                                        const float* __restrict__ cw,
                                                        const float* __restrict__ cb,
                                                        u16* __restrict__ uc)
{
    const int idx = blockIdx.x * 256 + threadIdx.x;   // over B*L*DI
    const int d  = idx & (DI_ - 1);
    const int bl = idx >> 11;
    const int l  = bl % L_;
    const int b  = bl / L_;
    const u16* u = xz + (size_t)b * L_ * (2 * DI_) + d;
    float acc = cb[d];
#pragma unroll
    for (int k = 0; k < DC_; k++) {
        const int ll = l + k - (DC_ - 1);
        if (ll >= 0) acc = fmaf(b2f(u[(size_t)ll * (2 * DI_)]), cw[d * DC_ + k], acc);
    }
    uc[(size_t)bl * DI_ + d] = f2b(silu_f(acc));
}

// ---------------- selective scan: one thread per (b, d), DS=16 states in regs ----------------
__global__ __launch_bounds__(256) void scan_kernel(const u16* __restrict__ dt,
                                                   const u16* __restrict__ uc,
                                                   const u16* __restrict__ xz,
                                                   const float* __restrict__ xdbl,
                                                   const float* __restrict__ A_log,
                                                   const float* __restrict__ D_ssm,
                                                   u16* __restrict__ y)
{
    const int idx = blockIdx.x * 256 + threadIdx.x;   // over B*DI
    const int d = idx & (DI_ - 1);
    const int b = idx >> 11;
    float A[DS_];
#pragma unroll
    for (int s = 0; s < DS_; s++) A[s] = -__expf(A_log[d * DS_ + s]);
    const float Dv = D_ssm[d];
    float h[DS_] = {};
    for (int l = 0; l < L_; l++) {
        const size_t bl = (size_t)b * L_ + l;
        const float dtv = b2f(dt[bl * DI_ + d]);
        const float uv  = b2f(uc[bl * DI_ + d]);
        const float zv  = b2f(xz[bl * (2 * DI_) + DI_ + d]);
        const float* Bp = xdbl + bl * (DTR_ + 2 * DS_) + DTR_;
        const float* Cp = Bp + DS_;
        float yv = 0.f;
#pragma unroll
        for (int s = 0; s < DS_; s++) {
            h[s] = fmaf(h[s], __expf(dtv * A[s]), dtv * Bp[s] * uv);
            yv = fmaf(h[s], Cp[s], yv);
        }
        yv = fmaf(uv, Dv, yv);
        yv *= silu_f(zv);
        y[bl * DI_ + d] = f2b(yv);
    }
}

// ---------------- classifier layer 2 ----------------
__global__ __launch_bounds__(256) void cls2_kernel(const float* __restrict__ c,
                                                   const float* __restrict__ b1,
                                                   const float* __restrict__ W2,
                                                   const float* __restrict__ b2,
                                                   float* __restrict__ out)
{
    const int b = blockIdx.x;
    float s = 0.f;
    for (int n = threadIdx.x; n < D_; n += 256) {
        float v = c[b * D_ + n] + b1[n];
        v = silu_f(v);
        s = fmaf(v, W2[n], s);
    }
#pragma unroll
    for (int o = 32; o > 0; o >>= 1) s += __shfl_down(s, o, 64);
    __shared__ float red[4];
    const int wid = threadIdx.x >> 6;
    if ((threadIdx.x & 63) == 0) red[wid] = s;
    __syncthreads();
    if (threadIdx.x == 0) out[b] = red[0] + red[1] + red[2] + red[3] + b2[0];
}

extern "C" void kernel_launch(void* const* d_in, const int* in_sizes, int n_in,
                              void* d_out, int out_size, void* d_ws, size_t ws_size,
                              hipStream_t stream)
{
    const float* x         = (const float*)d_in[0];
    const float* n1w       = (const float*)d_in[1];
    const float* n1b       = (const float*)d_in[2];
    const float* in_projW  = (const float*)d_in[3];
    const float* conv_w    = (const float*)d_in[4];
    const float* conv_b    = (const float*)d_in[5];
    const float* x_projW   = (const float*)d_in[6];
    const float* dt_projW  = (const float*)d_in[7];
    const float* dt_projb  = (const float*)d_in[8];
    const float* A_log     = (const float*)d_in[9];
    const float* D_ssm     = (const float*)d_in[10];
    const float* out_projW = (const float*)d_in[11];
    const float* n2w       = (const float*)d_in[12];
    const float* n2b       = (const float*)d_in[13];
    const float* ffn_W1    = (const float*)d_in[14];
    const float* ffn_b1    = (const float*)d_in[15];
    const float* ffn_W2    = (const float*)d_in[16];
    const float* ffn_b2    = (const float*)d_in[17];
    const float* cls_W1    = (const float*)d_in[18];
    const float* cls_b1    = (const float*)d_in[19];
    const float* cls_W2    = (const float*)d_in[20];
    const float* cls_b2    = (const float*)d_in[21];

    // ---- workspace layout ----
    float* ws   = (float*)d_ws;
    u16*   xz_b = (u16*)ws;                            // ROWS*4096 u16
    u16*   uc_b = xz_b + (size_t)ROWS * 4096;          // ROWS*2048 u16
    u16*   dt_b = uc_b + (size_t)ROWS * 2048;          // ROWS*2048 u16
    u16*   y_b  = dt_b + (size_t)ROWS * 2048;          // ROWS*2048 u16
    u16*   h_b  = y_b + (size_t)ROWS * 2048;           // ROWS*1024 u16
    float* x2   = (float*)(h_b + (size_t)ROWS * 1024); // ROWS*1024 f32
    float* xdbl = x2 + (size_t)ROWS * 1024;            // ROWS*96 f32
    u16*   wbuf = (u16*)(xdbl + (size_t)ROWS * 96);    // 4096*1024 u16
    float* clsh = (float*)(wbuf + (size_t)4096 * 1024);// 128*1024 f32

    float* outv = (float*)d_out;    // (B,1)
    float* x3   = outv + B_;        // (B,L,D)

    // 1. LN1 -> bf16
    ln_kernel<<<dim3(ROWS), dim3(256), 0, stream>>>(x, n1w, n1b, h_b);
    // 2. in_proj (MFMA) -> bf16 xz   (3968 x 4096, K=1024)
    f2b_kernel<<<dim3(4096 * 1024 / 8 / 256), dim3(256), 0, stream>>>(in_projW, wbuf, 4096 * 1024 / 8);
    gemm_mfma<0, false, false, true><<<dim3(4096 / 128, ROWS / 128), dim3(256), 0, stream>>>(
        h_b, wbuf, nullptr, nullptr, xz_b, ROWS, D_, 2 * DI_);
    // 3. causal conv + SiLU -> bf16
    conv_silu_kernel<<<dim3(ROWS * DI_ / 256), dim3(256), 0, stream>>>(xz_b, conv_w, conv_b, uc_b);
    // 4. x_proj (MFMA, N padded 96->128): xdbl = uc @ x_proj_W^T   (3968 x 96, K=2048)
    hipMemsetAsync(wbuf, 0, (size_t)128 * 2048 * sizeof(u16), stream);
    f2b_kernel<<<dim3(96 * 2048 / 8 / 256), dim3(256), 0, stream>>>(x_projW, wbuf, 96 * 2048 / 8);
    gemm_mfma<0, false, false, false><<<dim3(1, ROWS / 128), dim3(256), 0, stream>>>(
        uc_b, wbuf, nullptr, nullptr, xdbl, ROWS, DI_, DTR_ + 2 * DS_);
    // 5. dt_proj + softplus -> bf16   (3968 x 2048, K=64)
    gemm_f32<2, true, true><<<dim3(2048 / 64, ROWS / 64), dim3(256), 0, stream>>>(
        xdbl, DTR_ + 2 * DS_, dt_projW, dt_projb, dt_b, ROWS, DI_, DTR_);
    // 6. selective scan (+ skip + gate) -> bf16 y
    scan_kernel<<<dim3(B_ * DI_ / 256), dim3(256), 0, stream>>>(
        dt_b, uc_b, xz_b, xdbl, A_log, D_ssm, y_b);
    // 7. out_proj (MFMA) + residual: x2 = x + y @ out_proj_W^T   (3968 x 1024, K=2048)
    f2b_kernel<<<dim3(1024 * 2048 / 8 / 256), dim3(256), 0, stream>>>(out_projW, wbuf, 1024 * 2048 / 8);
    gemm_mfma<0, false, true, false><<<dim3(1024 / 128, ROWS / 128), dim3(256), 0, stream>>>(
        y_b, wbuf, nullptr, x, x2, ROWS, DI_, D_);
    // 8. LN2 -> bf16
    ln_kernel<<<dim3(ROWS), dim3(256), 0, stream>>>(x2, n2w, n2b, h_b);
    // 9. ffn1 (MFMA) + bias + SiLU -> bf16   (3968 x 2048, K=1024)
    f2b_kernel<<<dim3(2048 * 1024 / 8 / 256), dim3(256), 0, stream>>>(ffn_W1, wbuf, 2048 * 1024 / 8);
    gemm_mfma<1, true, false, true><<<dim3(2048 / 128, ROWS / 128), dim3(256), 0, stream>>>(
        h_b, wbuf, ffn_b1, nullptr, uc_b, ROWS, D_, 2 * D_);
    // 10. ffn2 (MFMA) + bias + residual -> x3 (d_out)   (3968 x 1024, K=2048)
    f2b_kernel<<<dim3(1024 * 2048 / 8 / 256), dim3(256), 0, stream>>>(ffn_W2, wbuf, 1024 * 2048 / 8);
    gemm_mfma<0, true, true, false><<<dim3(1024 / 128, ROWS / 128), dim3(256), 0, stream>>>(
        uc_b, wbuf, ffn_b2, x2, x3, ROWS, 2 * D_, D_);
    // 11. classifier layer 1: split-K MFMA, fused f32->bf16 staging
    hipMemsetAsync(clsh, 0, (size_t)B_ * D_ * sizeof(float), stream);
    gemm_cls_mfma<<<dim3(1024 / 128, KCLS / KCH), dim3(256), 0, stream>>>(x3, cls_W1, clsh);
    // 12. classifier layer 2
    cls2_kernel<<<dim3(B_), dim3(256), 0, stream>>>(clsh, cls_b1, cls_W2, cls_b2, outv);
}

// Round 4
// 437.458 us; speedup vs baseline: 3.7904x; 1.0823x over previous
//
#include <hip/hip_runtime.h>
#include <cstddef>
#include <cstdint>

#define B_   128
#define L_   31
#define D_   1024
#define DI_  2048
#define DS_  16
#define DC_  5
#define DTR_ 64
#define ROWS (B_ * L_)   // 3968
#define KCLS (L_ * D_)   // 31744

// weight-buffer offsets (u16 elements)
#define W_IN  0          // 4096x1024
#define W_OUT 4194304    // 1024x2048
#define W_F1  6291456    // 2048x1024
#define W_F2  8388608    // 1024x2048
#define W_XP  10485760   // 128x2048 (rows 96..127 zero)
#define W_DT  10747904   // 2048x64
#define WTOT  10878976

typedef unsigned short u16;
typedef __attribute__((ext_vector_type(8))) short s16x8;
typedef __attribute__((ext_vector_type(4))) float f32x4;

__device__ __forceinline__ float silu_f(float x) { return x / (1.0f + __expf(-x)); }

__device__ __forceinline__ u16 f2b(float f) {
    union { float f; uint32_t u; } c; c.f = f;
    uint32_t u = c.u + 0x7FFF + ((c.u >> 16) & 1);
    return (u16)(u >> 16);
}
__device__ __forceinline__ float b2f(u16 b) {
    union { uint32_t u; float f; } c; c.u = ((uint32_t)b) << 16;
    return c.f;
}
__device__ __forceinline__ uint32_t pack2(float lo, float hi) {
    return (uint32_t)f2b(lo) | ((uint32_t)f2b(hi) << 16);
}
__device__ __forceinline__ void cvt8(const float* __restrict__ s, u16* __restrict__ d) {
    const float4* p = (const float4*)s;
    float4 a = p[0], b = p[1];
    uint4 r;
    r.x = pack2(a.x, a.y); r.y = pack2(a.z, a.w);
    r.z = pack2(b.x, b.y); r.w = pack2(b.z, b.w);
    *(uint4*)d = r;
}

#define GLD16(g, s) __builtin_amdgcn_global_load_lds( \
    (const __attribute__((address_space(1))) void*)(g), \
    (__attribute__((address_space(3))) void*)(s), 16, 0, 0)

// ---------------- all-weights fp32 -> bf16 (single launch) ----------------
__global__ __launch_bounds__(256) void f2b_all_kernel(
    const float* __restrict__ inW, const float* __restrict__ outW,
    const float* __restrict__ f1W, const float* __restrict__ f2W,
    const float* __restrict__ xpW, const float* __restrict__ dtW,
    u16* __restrict__ wbuf)
{
    int g = blockIdx.x * 256 + threadIdx.x;
    if (g < 524288) { cvt8(inW + (size_t)g * 8, wbuf + W_IN + (size_t)g * 8); return; }
    g -= 524288;
    if (g < 262144) { cvt8(outW + (size_t)g * 8, wbuf + W_OUT + (size_t)g * 8); return; }
    g -= 262144;
    if (g < 262144) { cvt8(f1W + (size_t)g * 8, wbuf + W_F1 + (size_t)g * 8); return; }
    g -= 262144;
    if (g < 262144) { cvt8(f2W + (size_t)g * 8, wbuf + W_F2 + (size_t)g * 8); return; }
    g -= 262144;
    if (g < 32768) {   // x_proj, padded 96 -> 128 rows
        const int row = g >> 8, col8 = (g & 255) * 8;
        u16* d = wbuf + W_XP + (size_t)row * 2048 + col8;
        if (row < 96) cvt8(xpW + (size_t)row * 2048 + col8, d);
        else *(uint4*)d = make_uint4(0, 0, 0, 0);
        return;
    }
    g -= 32768;
    if (g < 16384) cvt8(dtW + (size_t)g * 8, wbuf + W_DT + (size_t)g * 8);
}

// ---------------- LayerNorm (one block per row, D=1024) -> bf16 out ----------------
__global__ __launch_bounds__(256) void ln_kernel(const float* __restrict__ x,
                                                 const float* __restrict__ w,
                                                 const float* __restrict__ b,
                                                 u16* __restrict__ y)
{
    const int row = blockIdx.x;
    const float* xr = x + (size_t)row * D_;
    float v[4];
    float sum = 0.f, sq = 0.f;
#pragma unroll
    for (int i = 0; i < 4; i++) {
        v[i] = xr[threadIdx.x + i * 256];
        sum += v[i];
        sq  += v[i] * v[i];
    }
#pragma unroll
    for (int o = 32; o > 0; o >>= 1) {
        sum += __shfl_down(sum, o, 64);
        sq  += __shfl_down(sq, o, 64);
    }
    __shared__ float red[8];
    const int wid = threadIdx.x >> 6;
    if ((threadIdx.x & 63) == 0) { red[wid] = sum; red[4 + wid] = sq; }
    __syncthreads();
    sum = red[0] + red[1] + red[2] + red[3];
    sq  = red[4] + red[5] + red[6] + red[7];
    const float mean = sum * (1.0f / D_);
    const float var  = sq * (1.0f / D_) - mean * mean;
    const float rstd = rsqrtf(var + 1e-5f);
    u16* yr = y + (size_t)row * D_;
#pragma unroll
    for (int i = 0; i < 4; i++) {
        const int c = threadIdx.x + i * 256;
        yr[c] = f2b((v[i] - mean) * rstd * w[c] + b[c]);
    }
}

// ---------------- bf16 MFMA GEMM: C[M,Nout](+)= A[M,K] @ W[Npad,K]^T ----------------
// m97 structure: 128x128 tile, BK=32, 4 waves (2x2), global_load_lds width 16,
// 16x16x32 MFMA, C/D layout col=lane&15, row=(lane>>4)*4+reg (m89-verified).
// ACT: 0 none, 1 silu, 2 softplus. OUT: 0 f32 store, 1 bf16 store, 2 f32 atomicAdd.
// kLen: K-chunk per z-block (== K when gridDim.z == 1).
template <int ACT, bool BIAS, bool RES, int OUT>
__global__ __launch_bounds__(256) void gemm_mfma(
    const u16* __restrict__ A, const u16* __restrict__ W,
    const float* __restrict__ bias, const float* __restrict__ res,
    void* __restrict__ Cout, int M, int K, int Nout, int kLen)
{
    __shared__ __align__(16) u16 As[128 * 32];
    __shared__ __align__(16) u16 Bs[128 * 32];
    const int tid = threadIdx.x;
    const int l = tid & 63, w = tid >> 6;
    const int bm = blockIdx.y * 128, bn = blockIdx.x * 128;
    const int kOff = blockIdx.z * kLen;

    const int sr = l >> 2;           // 0..15 row within 16-row chunk
    const int sk = (l & 3) * 8;      // k-element offset (16B granules)
    const u16* gA = A + (size_t)(bm + w * 16 + sr) * K + kOff + sk;
    const u16* gB = W + (size_t)(bn + w * 16 + sr) * K + kOff + sk;
    u16* lA = As + (w * 16 + sr) * 32 + sk;
    u16* lB = Bs + (w * 16 + sr) * 32 + sk;

    const int lane15 = l & 15, lhi = l >> 4;
    const int wr = w >> 1, wc = w & 1;
    const u16* fA = As + (wr * 64 + lane15) * 32 + lhi * 8;
    const u16* fB = Bs + (wc * 64 + lane15) * 32 + lhi * 8;

    f32x4 acc[4][4] = {};

    for (int kk = 0; kk < kLen; kk += 32) {
        GLD16(gA, lA); GLD16(gA + (size_t)64 * K, lA + 64 * 32);
        GLD16(gB, lB); GLD16(gB + (size_t)64 * K, lB + 64 * 32);
        gA += 32; gB += 32;
        __syncthreads();
        s16x8 af[4], bfr[4];
#pragma unroll
        for (int mi = 0; mi < 4; mi++) af[mi]  = *(const s16x8*)(fA + mi * 16 * 32);
#pragma unroll
        for (int ni = 0; ni < 4; ni++) bfr[ni] = *(const s16x8*)(fB + ni * 16 * 32);
#pragma unroll
        for (int mi = 0; mi < 4; mi++)
#pragma unroll
            for (int ni = 0; ni < 4; ni++)
                acc[mi][ni] = __builtin_amdgcn_mfma_f32_16x16x32_bf16(
                    af[mi], bfr[ni], acc[mi][ni], 0, 0, 0);
        __syncthreads();
    }

#pragma unroll
    for (int ni = 0; ni < 4; ni++) {
        const int col = bn + wc * 64 + ni * 16 + lane15;
        if (col >= Nout) continue;
        const float bv = BIAS ? bias[col] : 0.0f;
#pragma unroll
        for (int mi = 0; mi < 4; mi++) {
#pragma unroll
            for (int r = 0; r < 4; r++) {
                const int row = bm + wr * 64 + mi * 16 + lhi * 4 + r;
                float v = acc[mi][ni][r] + bv;
                if (ACT == 1) v = silu_f(v);
                if (ACT == 2) v = (v > 20.0f) ? v : log1pf(__expf(v));
                if (RES) v += res[(size_t)row * Nout + col];
                if (OUT == 0) ((float*)Cout)[(size_t)row * Nout + col] = v;
                if (OUT == 1) ((u16*)Cout)[(size_t)row * Nout + col] = f2b(v);
                if (OUT == 2) atomicAdd(&((float*)Cout)[(size_t)row * Nout + col], v);
            }
        }
    }
}

// ---------------- classifier layer 1: split-K MFMA with fused f32->bf16 staging ----------------
#define KCH 512
__global__ __launch_bounds__(256) void gemm_cls_mfma(
    const float* __restrict__ A, const float* __restrict__ W,
    float* __restrict__ C)
{
    __shared__ __align__(16) u16 As[128 * 32];
    __shared__ __align__(16) u16 Bs[128 * 32];
    const int tid = threadIdx.x;
    const int l = tid & 63, w = tid >> 6;
    const int bn = blockIdx.x * 128;
    const int k0 = blockIdx.y * KCH;

    const int sr = l >> 2;
    const int sk = (l & 3) * 8;
    const int row = w * 16 + sr;
    const float* gA0 = A + (size_t)row * KCLS + k0 + sk;
    const float* gA1 = gA0 + (size_t)64 * KCLS;
    const float* gB0 = W + (size_t)(bn + row) * KCLS + k0 + sk;
    const float* gB1 = gB0 + (size_t)64 * KCLS;
    u16* lA0 = As + row * 32 + sk;  u16* lA1 = lA0 + 64 * 32;
    u16* lB0 = Bs + row * 32 + sk;  u16* lB1 = lB0 + 64 * 32;

    const int lane15 = l & 15, lhi = l >> 4;
    const int wr = w >> 1, wc = w & 1;
    const u16* fA = As + (wr * 64 + lane15) * 32 + lhi * 8;
    const u16* fB = Bs + (wc * 64 + lane15) * 32 + lhi * 8;

    f32x4 acc[4][4] = {};

    for (int ks = 0; ks < KCH / 32; ks++) {
        float4 a00 = *(const float4*)(gA0);     float4 a01 = *(const float4*)(gA0 + 4);
        float4 a10 = *(const float4*)(gA1);     float4 a11 = *(const float4*)(gA1 + 4);
        float4 b00 = *(const float4*)(gB0);     float4 b01 = *(const float4*)(gB0 + 4);
        float4 b10 = *(const float4*)(gB1);     float4 b11 = *(const float4*)(gB1 + 4);
        gA0 += 32; gA1 += 32; gB0 += 32; gB1 += 32;
        __syncthreads();
        uint4 r;
        r.x = pack2(a00.x, a00.y); r.y = pack2(a00.z, a00.w);
        r.z = pack2(a01.x, a01.y); r.w = pack2(a01.z, a01.w);
        *(uint4*)lA0 = r;
        r.x = pack2(a10.x, a10.y); r.y = pack2(a10.z, a10.w);
        r.z = pack2(a11.x, a11.y); r.w = pack2(a11.z, a11.w);
        *(uint4*)lA1 = r;
        r.x = pack2(b00.x, b00.y); r.y = pack2(b00.z, b00.w);
        r.z = pack2(b01.x, b01.y); r.w = pack2(b01.z, b01.w);
        *(uint4*)lB0 = r;
        r.x = pack2(b10.x, b10.y); r.y = pack2(b10.z, b10.w);
        r.z = pack2(b11.x, b11.y); r.w = pack2(b11.z, b11.w);
        *(uint4*)lB1 = r;
        __syncthreads();
        s16x8 af[4], bfr[4];
#pragma unroll
        for (int mi = 0; mi < 4; mi++) af[mi]  = *(const s16x8*)(fA + mi * 16 * 32);
#pragma unroll
        for (int ni = 0; ni < 4; ni++) bfr[ni] = *(const s16x8*)(fB + ni * 16 * 32);
#pragma unroll
        for (int mi = 0; mi < 4; mi++)
#pragma unroll
            for (int ni = 0; ni < 4; ni++)
                acc[mi][ni] = __builtin_amdgcn_mfma_f32_16x16x32_bf16(
                    af[mi], bfr[ni], acc[mi][ni], 0, 0, 0);
    }

#pragma unroll
    for (int ni = 0; ni < 4; ni++) {
        const int col = bn + wc * 64 + ni * 16 + lane15;
#pragma unroll
        for (int mi = 0; mi < 4; mi++) {
#pragma unroll
            for (int r = 0; r < 4; r++) {
                const int m = wr * 64 + mi * 16 + lhi * 4 + r;
                atomicAdd(&C[(size_t)m * 1024 + col], acc[mi][ni][r]);
            }
        }
    }
}

// ---------------- causal depthwise conv1d (DC=5) + SiLU -> bf16 (bf16 in) ----------------
__global__ __launch_bounds__(256) void conv_silu_kernel(const u16* __restrict__ xz,
                                                        const float* __restrict__ cw,
                                                        const float* __restrict__ cb,
                                                        u16* __restrict__ uc)
{
    const int idx = blockIdx.x * 256 + threadIdx.x;   // over B*L*DI
    const int d  = idx & (DI_ - 1);
    const int bl = idx >> 11;
    const int l  = bl % L_;
    const int b  = bl / L_;
    const u16* u = xz + (size_t)b * L_ * (2 * DI_) + d;
    float acc = cb[d];
#pragma unroll
    for (int k = 0; k < DC_; k++) {
        const int ll = l + k - (DC_ - 1);
        if (ll >= 0) acc = fmaf(b2f(u[(size_t)ll * (2 * DI_)]), cw[d * DC_ + k], acc);
    }
    uc[(size_t)bl * DI_ + d] = f2b(silu_f(acc));
}

// ---------------- extract xdbl[:, 0:64] -> bf16 (dt_proj A operand) ----------------
__global__ __launch_bounds__(256) void dtext_kernel(const float* __restrict__ xdbl,
                                                    u16* __restrict__ dtb)
{
    const int idx = blockIdx.x * 256 + threadIdx.x;   // over ROWS*16
    const int row = idx >> 4, c4 = (idx & 15) * 4;
    float4 v = *(const float4*)(xdbl + (size_t)row * 96 + c4);
    uint2 r;
    r.x = pack2(v.x, v.y); r.y = pack2(v.z, v.w);
    *(uint2*)(dtb + (size_t)row * 64 + c4) = r;
}

// ---------------- selective scan: one thread per (b, d), DS=16 states in regs ----------------
__global__ __launch_bounds__(256) void scan_kernel(const u16* __restrict__ dt,
                                                   const u16* __restrict__ uc,
                                                   const u16* __restrict__ xz,
                                                   const float* __restrict__ xdbl,
                                                   const float* __restrict__ A_log,
                                                   const float* __restrict__ D_ssm,
                                                   u16* __restrict__ y)
{
    const int idx = blockIdx.x * 256 + threadIdx.x;   // over B*DI
    const int d = idx & (DI_ - 1);
    const int b = idx >> 11;
    float A[DS_];
#pragma unroll
    for (int s = 0; s < DS_; s++) A[s] = -__expf(A_log[d * DS_ + s]);
    const float Dv = D_ssm[d];
    float h[DS_] = {};
    for (int l = 0; l < L_; l++) {
        const size_t bl = (size_t)b * L_ + l;
        const float dtv = b2f(dt[bl * DI_ + d]);
        const float uv  = b2f(uc[bl * DI_ + d]);
        const float zv  = b2f(xz[bl * (2 * DI_) + DI_ + d]);
        const float* Bp = xdbl + bl * (DTR_ + 2 * DS_) + DTR_;
        const float* Cp = Bp + DS_;
        float yv = 0.f;
#pragma unroll
        for (int s = 0; s < DS_; s++) {
            h[s] = fmaf(h[s], __expf(dtv * A[s]), dtv * Bp[s] * uv);
            yv = fmaf(h[s], Cp[s], yv);
        }
        yv = fmaf(uv, Dv, yv);
        yv *= silu_f(zv);
        y[bl * DI_ + d] = f2b(yv);
    }
}

// ---------------- classifier layer 2 ----------------
__global__ __launch_bounds__(256) void cls2_kernel(const float* __restrict__ c,
                                                   const float* __restrict__ b1,
                                                   const float* __restrict__ W2,
                                                   const float* __restrict__ b2,
                                                   float* __restrict__ out)
{
    const int b = blockIdx.x;
    float s = 0.f;
    for (int n = threadIdx.x; n < D_; n += 256) {
        float v = c[b * D_ + n] + b1[n];
        v = silu_f(v);
        s = fmaf(v, W2[n], s);
    }
#pragma unroll
    for (int o = 32; o > 0; o >>= 1) s += __shfl_down(s, o, 64);
    __shared__ float red[4];
    const int wid = threadIdx.x >> 6;
    if ((threadIdx.x & 63) == 0) red[wid] = s;
    __syncthreads();
    if (threadIdx.x == 0) out[b] = red[0] + red[1] + red[2] + red[3] + b2[0];
}

extern "C" void kernel_launch(void* const* d_in, const int* in_sizes, int n_in,
                              void* d_out, int out_size, void* d_ws, size_t ws_size,
                              hipStream_t stream)
{
    const float* x         = (const float*)d_in[0];
    const float* n1w       = (const float*)d_in[1];
    const float* n1b       = (const float*)d_in[2];
    const float* in_projW  = (const float*)d_in[3];
    const float* conv_w    = (const float*)d_in[4];
    const float* conv_b    = (const float*)d_in[5];
    const float* x_projW   = (const float*)d_in[6];
    const float* dt_projW  = (const float*)d_in[7];
    const float* dt_projb  = (const float*)d_in[8];
    const float* A_log     = (const float*)d_in[9];
    const float* D_ssm     = (const float*)d_in[10];
    const float* out_projW = (const float*)d_in[11];
    const float* n2w       = (const float*)d_in[12];
    const float* n2b       = (const float*)d_in[13];
    const float* ffn_W1    = (const float*)d_in[14];
    const float* ffn_b1    = (const float*)d_in[15];
    const float* ffn_W2    = (const float*)d_in[16];
    const float* ffn_b2    = (const float*)d_in[17];
    const float* cls_W1    = (const float*)d_in[18];
    const float* cls_b1    = (const float*)d_in[19];
    const float* cls_W2    = (const float*)d_in[20];
    const float* cls_b2    = (const float*)d_in[21];

    // ---- workspace layout ----
    float* ws   = (float*)d_ws;
    u16*   xz_b = (u16*)ws;                            // ROWS*4096 u16
    u16*   uc_b = xz_b + (size_t)ROWS * 4096;          // ROWS*2048
    u16*   dt_b = uc_b + (size_t)ROWS * 2048;          // ROWS*2048
    u16*   y_b  = dt_b + (size_t)ROWS * 2048;          // ROWS*2048
    u16*   h_b  = y_b + (size_t)ROWS * 2048;           // ROWS*1024
    float* x2   = (float*)(h_b + (size_t)ROWS * 1024); // ROWS*1024 f32
    float* xdbl = x2 + (size_t)ROWS * 1024;            // ROWS*96 f32
    u16*   dtb  = (u16*)(xdbl + (size_t)ROWS * 96);    // ROWS*64 u16
    u16*   wbuf = dtb + (size_t)ROWS * 64;             // WTOT u16
    float* clsh = (float*)(wbuf + (size_t)WTOT);       // 128*1024 f32

    float* outv = (float*)d_out;    // (B,1)
    float* x3   = outv + B_;        // (B,L,D)

    // 0. all weight conversions (independent of activations)
    f2b_all_kernel<<<dim3(5312), dim3(256), 0, stream>>>(
        in_projW, out_projW, ffn_W1, ffn_W2, x_projW, dt_projW, wbuf);
    // 1. LN1 -> bf16
    ln_kernel<<<dim3(ROWS), dim3(256), 0, stream>>>(x, n1w, n1b, h_b);
    // 2. in_proj (MFMA) -> bf16 xz   (3968 x 4096, K=1024)
    gemm_mfma<0, false, false, 1><<<dim3(32, 31, 1), dim3(256), 0, stream>>>(
        h_b, wbuf + W_IN, nullptr, nullptr, xz_b, ROWS, D_, 2 * DI_, D_);
    // 3. causal conv + SiLU -> bf16
    conv_silu_kernel<<<dim3(ROWS * DI_ / 256), dim3(256), 0, stream>>>(xz_b, conv_w, conv_b, uc_b);
    // 4. x_proj (split-K MFMA, atomic f32): xdbl = uc @ x_proj_W^T   (3968 x 96, K=2048)
    hipMemsetAsync(xdbl, 0, (size_t)ROWS * 96 * sizeof(float), stream);
    gemm_mfma<0, false, false, 2><<<dim3(1, 31, 4), dim3(256), 0, stream>>>(
        uc_b, wbuf + W_XP, nullptr, nullptr, xdbl, ROWS, DI_, DTR_ + 2 * DS_, 512);
    // 5. dt_proj (MFMA, softplus) -> bf16   (3968 x 2048, K=64)
    dtext_kernel<<<dim3(ROWS * 16 / 256), dim3(256), 0, stream>>>(xdbl, dtb);
    gemm_mfma<2, true, false, 1><<<dim3(16, 31, 1), dim3(256), 0, stream>>>(
        dtb, wbuf + W_DT, dt_projb, nullptr, dt_b, ROWS, DTR_, DI_, DTR_);
    // 6. selective scan (+ skip + gate) -> bf16 y
    scan_kernel<<<dim3(B_ * DI_ / 256), dim3(256), 0, stream>>>(
        dt_b, uc_b, xz_b, xdbl, A_log, D_ssm, y_b);
    // 7. out_proj (MFMA) + residual: x2 = x + y @ out_proj_W^T   (3968 x 1024, K=2048)
    gemm_mfma<0, false, true, 0><<<dim3(8, 31, 1), dim3(256), 0, stream>>>(
        y_b, wbuf + W_OUT, nullptr, x, x2, ROWS, DI_, D_, DI_);
    // 8. LN2 -> bf16
    ln_kernel<<<dim3(ROWS), dim3(256), 0, stream>>>(x2, n2w, n2b, h_b);
    // 9. ffn1 (MFMA) + bias + SiLU -> bf16   (3968 x 2048, K=1024)
    gemm_mfma<1, true, false, 1><<<dim3(16, 31, 1), dim3(256), 0, stream>>>(
        h_b, wbuf + W_F1, ffn_b1, nullptr, uc_b, ROWS, D_, 2 * D_, D_);
    // 10. ffn2 (MFMA) + bias + residual -> x3 (d_out)   (3968 x 1024, K=2048)
    gemm_mfma<0, true, true, 0><<<dim3(8, 31, 1), dim3(256), 0, stream>>>(
        uc_b, wbuf + W_F2, ffn_b2, x2, x3, ROWS, 2 * D_, D_, 2 * D_);
    // 11. classifier layer 1: split-K MFMA, fused f32->bf16 staging
    hipMemsetAsync(clsh, 0, (size_t)B_ * D_ * sizeof(float), stream);
    gemm_cls_mfma<<<dim3(1024 / 128, KCLS / KCH), dim3(256), 0, stream>>>(x3, cls_W1, clsh);
    // 12. classifier layer 2
    cls2_kernel<<<dim3(B_), dim3(256), 0, stream>>>(clsh, cls_b1, cls_W2, cls_b2, outv);
}

// Round 5
// 425.598 us; speedup vs baseline: 3.8960x; 1.0279x over previous
//
#include <hip/hip_runtime.h>
#include <cstddef>
#include <cstdint>

#define B_   128
#define L_   31
#define D_   1024
#define DI_  2048
#define DS_  16
#define DC_  5
#define DTR_ 64
#define ROWS (B_ * L_)   // 3968
#define KCLS (L_ * D_)   // 31744

// weight-buffer offsets (u16 elements)
#define W_IN  0          // 4096x1024
#define W_OUT 4194304    // 1024x2048
#define W_F1  6291456    // 2048x1024
#define W_F2  8388608    // 1024x2048
#define W_XP  10485760   // 128x2048 (rows 96..127 zero)
#define W_DT  10747904   // 2048x64
#define WTOT  10878976

typedef unsigned short u16;
typedef __attribute__((ext_vector_type(8))) short s16x8;
typedef __attribute__((ext_vector_type(4))) float f32x4;

__device__ __forceinline__ float silu_f(float x) { return x / (1.0f + __expf(-x)); }

__device__ __forceinline__ u16 f2b(float f) {
    union { float f; uint32_t u; } c; c.f = f;
    uint32_t u = c.u + 0x7FFF + ((c.u >> 16) & 1);
    return (u16)(u >> 16);
}
__device__ __forceinline__ float b2f(u16 b) {
    union { uint32_t u; float f; } c; c.u = ((uint32_t)b) << 16;
    return c.f;
}
__device__ __forceinline__ uint32_t pack2(float lo, float hi) {
    return (uint32_t)f2b(lo) | ((uint32_t)f2b(hi) << 16);
}
__device__ __forceinline__ void cvt8(const float* __restrict__ s, u16* __restrict__ d) {
    const float4* p = (const float4*)s;
    float4 a = p[0], b = p[1];
    uint4 r;
    r.x = pack2(a.x, a.y); r.y = pack2(a.z, a.w);
    r.z = pack2(b.x, b.y); r.w = pack2(b.z, b.w);
    *(uint4*)d = r;
}

#define GLD16(g, s) __builtin_amdgcn_global_load_lds( \
    (const __attribute__((address_space(1))) void*)(g), \
    (__attribute__((address_space(3))) void*)(s), 16, 0, 0)

// ---------------- all-weights fp32 -> bf16 (single launch) ----------------
__global__ __launch_bounds__(256) void f2b_all_kernel(
    const float* __restrict__ inW, const float* __restrict__ outW,
    const float* __restrict__ f1W, const float* __restrict__ f2W,
    const float* __restrict__ xpW, const float* __restrict__ dtW,
    u16* __restrict__ wbuf)
{
    int g = blockIdx.x * 256 + threadIdx.x;
    if (g < 524288) { cvt8(inW + (size_t)g * 8, wbuf + W_IN + (size_t)g * 8); return; }
    g -= 524288;
    if (g < 262144) { cvt8(outW + (size_t)g * 8, wbuf + W_OUT + (size_t)g * 8); return; }
    g -= 262144;
    if (g < 262144) { cvt8(f1W + (size_t)g * 8, wbuf + W_F1 + (size_t)g * 8); return; }
    g -= 262144;
    if (g < 262144) { cvt8(f2W + (size_t)g * 8, wbuf + W_F2 + (size_t)g * 8); return; }
    g -= 262144;
    if (g < 32768) {   // x_proj, padded 96 -> 128 rows
        const int row = g >> 8, col8 = (g & 255) * 8;
        u16* d = wbuf + W_XP + (size_t)row * 2048 + col8;
        if (row < 96) cvt8(xpW + (size_t)row * 2048 + col8, d);
        else *(uint4*)d = make_uint4(0, 0, 0, 0);
        return;
    }
    g -= 32768;
    if (g < 16384) cvt8(dtW + (size_t)g * 8, wbuf + W_DT + (size_t)g * 8);
}

// ---------------- LayerNorm (one block per row, D=1024) -> bf16 out ----------------
__global__ __launch_bounds__(256) void ln_kernel(const float* __restrict__ x,
                                                 const float* __restrict__ w,
                                                 const float* __restrict__ b,
                                                 u16* __restrict__ y)
{
    const int row = blockIdx.x;
    const float* xr = x + (size_t)row * D_;
    float v[4];
    float sum = 0.f, sq = 0.f;
#pragma unroll
    for (int i = 0; i < 4; i++) {
        v[i] = xr[threadIdx.x + i * 256];
        sum += v[i];
        sq  += v[i] * v[i];
    }
#pragma unroll
    for (int o = 32; o > 0; o >>= 1) {
        sum += __shfl_down(sum, o, 64);
        sq  += __shfl_down(sq, o, 64);
    }
    __shared__ float red[8];
    const int wid = threadIdx.x >> 6;
    if ((threadIdx.x & 63) == 0) { red[wid] = sum; red[4 + wid] = sq; }
    __syncthreads();
    sum = red[0] + red[1] + red[2] + red[3];
    sq  = red[4] + red[5] + red[6] + red[7];
    const float mean = sum * (1.0f / D_);
    const float var  = sq * (1.0f / D_) - mean * mean;
    const float rstd = rsqrtf(var + 1e-5f);
    u16* yr = y + (size_t)row * D_;
#pragma unroll
    for (int i = 0; i < 4; i++) {
        const int c = threadIdx.x + i * 256;
        yr[c] = f2b((v[i] - mean) * rstd * w[c] + b[c]);
    }
}

// ---------------- fused: x2 = x + p0 + p1; h2 = LN(x2) -> bf16 ----------------
__global__ __launch_bounds__(256) void ln2_fuse_kernel(const float* __restrict__ x,
                                                       const float* __restrict__ p0,
                                                       const float* __restrict__ p1,
                                                       const float* __restrict__ w,
                                                       const float* __restrict__ b,
                                                       float* __restrict__ x2,
                                                       u16* __restrict__ y)
{
    const int row = blockIdx.x;
    const size_t base = (size_t)row * D_;
    float v[4];
    float sum = 0.f, sq = 0.f;
#pragma unroll
    for (int i = 0; i < 4; i++) {
        const int c = threadIdx.x + i * 256;
        const float s = x[base + c] + p0[base + c] + p1[base + c];
        x2[base + c] = s;
        v[i] = s;
        sum += s;
        sq  += s * s;
    }
#pragma unroll
    for (int o = 32; o > 0; o >>= 1) {
        sum += __shfl_down(sum, o, 64);
        sq  += __shfl_down(sq, o, 64);
    }
    __shared__ float red[8];
    const int wid = threadIdx.x >> 6;
    if ((threadIdx.x & 63) == 0) { red[wid] = sum; red[4 + wid] = sq; }
    __syncthreads();
    sum = red[0] + red[1] + red[2] + red[3];
    sq  = red[4] + red[5] + red[6] + red[7];
    const float mean = sum * (1.0f / D_);
    const float var  = sq * (1.0f / D_) - mean * mean;
    const float rstd = rsqrtf(var + 1e-5f);
    u16* yr = y + base;
#pragma unroll
    for (int i = 0; i < 4; i++) {
        const int c = threadIdx.x + i * 256;
        yr[c] = f2b((v[i] - mean) * rstd * w[c] + b[c]);
    }
}

// ---------------- x3 = x2 + q0 + q1 + b2 (vectorized) ----------------
__global__ __launch_bounds__(256) void add3_bias_kernel(const float* __restrict__ x2,
                                                        const float* __restrict__ q0,
                                                        const float* __restrict__ q1,
                                                        const float* __restrict__ b2,
                                                        float* __restrict__ x3)
{
    const int i = blockIdx.x * 256 + threadIdx.x;   // float4 index over ROWS*1024/4
    float4 a  = ((const float4*)x2)[i];
    float4 c0 = ((const float4*)q0)[i];
    float4 c1 = ((const float4*)q1)[i];
    float4 bb = ((const float4*)b2)[i & 255];       // row stride = 256 float4
    float4 r;
    r.x = a.x + c0.x + c1.x + bb.x;
    r.y = a.y + c0.y + c1.y + bb.y;
    r.z = a.z + c0.z + c1.z + bb.z;
    r.w = a.w + c0.w + c1.w + bb.w;
    ((float4*)x3)[i] = r;
}

// ---------------- bf16 MFMA GEMM: C[M,Nout](+)= A[M,K] @ W[Npad,K]^T ----------------
// m97 structure: 128x128 tile, BK=32, 4 waves (2x2), global_load_lds width 16.
// ACT: 0 none, 1 silu, 2 softplus.
// OUT: 0 f32 store, 1 bf16 store, 2 f32 atomicAdd, 3 f32 store to per-z partial
//      buffer (Cout + z*M*Nout; no bias/res/act applied by caller convention).
template <int ACT, bool BIAS, bool RES, int OUT>
__global__ __launch_bounds__(256) void gemm_mfma(
    const u16* __restrict__ A, const u16* __restrict__ W,
    const float* __restrict__ bias, const float* __restrict__ res,
    void* __restrict__ Cout, int M, int K, int Nout, int kLen)
{
    __shared__ __align__(16) u16 As[128 * 32];
    __shared__ __align__(16) u16 Bs[128 * 32];
    const int tid = threadIdx.x;
    const int l = tid & 63, w = tid >> 6;
    const int bm = blockIdx.y * 128, bn = blockIdx.x * 128;
    const int kOff = blockIdx.z * kLen;

    const int sr = l >> 2;           // 0..15 row within 16-row chunk
    const int sk = (l & 3) * 8;      // k-element offset (16B granules)
    const u16* gA = A + (size_t)(bm + w * 16 + sr) * K + kOff + sk;
    const u16* gB = W + (size_t)(bn + w * 16 + sr) * K + kOff + sk;
    u16* lA = As + (w * 16 + sr) * 32 + sk;
    u16* lB = Bs + (w * 16 + sr) * 32 + sk;

    const int lane15 = l & 15, lhi = l >> 4;
    const int wr = w >> 1, wc = w & 1;
    const u16* fA = As + (wr * 64 + lane15) * 32 + lhi * 8;
    const u16* fB = Bs + (wc * 64 + lane15) * 32 + lhi * 8;

    f32x4 acc[4][4] = {};

    for (int kk = 0; kk < kLen; kk += 32) {
        GLD16(gA, lA); GLD16(gA + (size_t)64 * K, lA + 64 * 32);
        GLD16(gB, lB); GLD16(gB + (size_t)64 * K, lB + 64 * 32);
        gA += 32; gB += 32;
        __syncthreads();
        s16x8 af[4], bfr[4];
#pragma unroll
        for (int mi = 0; mi < 4; mi++) af[mi]  = *(const s16x8*)(fA + mi * 16 * 32);
#pragma unroll
        for (int ni = 0; ni < 4; ni++) bfr[ni] = *(const s16x8*)(fB + ni * 16 * 32);
#pragma unroll
        for (int mi = 0; mi < 4; mi++)
#pragma unroll
            for (int ni = 0; ni < 4; ni++)
                acc[mi][ni] = __builtin_amdgcn_mfma_f32_16x16x32_bf16(
                    af[mi], bfr[ni], acc[mi][ni], 0, 0, 0);
        __syncthreads();
    }

#pragma unroll
    for (int ni = 0; ni < 4; ni++) {
        const int col = bn + wc * 64 + ni * 16 + lane15;
        if (col >= Nout) continue;
        const float bv = BIAS ? bias[col] : 0.0f;
#pragma unroll
        for (int mi = 0; mi < 4; mi++) {
#pragma unroll
            for (int r = 0; r < 4; r++) {
                const int row = bm + wr * 64 + mi * 16 + lhi * 4 + r;
                float v = acc[mi][ni][r] + bv;
                if (ACT == 1) v = silu_f(v);
                if (ACT == 2) v = (v > 20.0f) ? v : log1pf(__expf(v));
                if (RES) v += res[(size_t)row * Nout + col];
                if (OUT == 0) ((float*)Cout)[(size_t)row * Nout + col] = v;
                if (OUT == 1) ((u16*)Cout)[(size_t)row * Nout + col] = f2b(v);
                if (OUT == 2) atomicAdd(&((float*)Cout)[(size_t)row * Nout + col], v);
                if (OUT == 3) ((float*)Cout)[((size_t)blockIdx.z * M + row) * Nout + col] = v;
            }
        }
    }
}

// ---------------- classifier layer 1: split-K MFMA with fused f32->bf16 staging ----------------
#define KCH 512
__global__ __launch_bounds__(256) void gemm_cls_mfma(
    const float* __restrict__ A, const float* __restrict__ W,
    float* __restrict__ C)
{
    __shared__ __align__(16) u16 As[128 * 32];
    __shared__ __align__(16) u16 Bs[128 * 32];
    const int tid = threadIdx.x;
    const int l = tid & 63, w = tid >> 6;
    const int bn = blockIdx.x * 128;
    const int k0 = blockIdx.y * KCH;

    const int sr = l >> 2;
    const int sk = (l & 3) * 8;
    const int row = w * 16 + sr;
    const float* gA0 = A + (size_t)row * KCLS + k0 + sk;
    const float* gA1 = gA0 + (size_t)64 * KCLS;
    const float* gB0 = W + (size_t)(bn + row) * KCLS + k0 + sk;
    const float* gB1 = gB0 + (size_t)64 * KCLS;
    u16* lA0 = As + row * 32 + sk;  u16* lA1 = lA0 + 64 * 32;
    u16* lB0 = Bs + row * 32 + sk;  u16* lB1 = lB0 + 64 * 32;

    const int lane15 = l & 15, lhi = l >> 4;
    const int wr = w >> 1, wc = w & 1;
    const u16* fA = As + (wr * 64 + lane15) * 32 + lhi * 8;
    const u16* fB = Bs + (wc * 64 + lane15) * 32 + lhi * 8;

    f32x4 acc[4][4] = {};

    for (int ks = 0; ks < KCH / 32; ks++) {
        float4 a00 = *(const float4*)(gA0);     float4 a01 = *(const float4*)(gA0 + 4);
        float4 a10 = *(const float4*)(gA1);     float4 a11 = *(const float4*)(gA1 + 4);
        float4 b00 = *(const float4*)(gB0);     float4 b01 = *(const float4*)(gB0 + 4);
        float4 b10 = *(const float4*)(gB1);     float4 b11 = *(const float4*)(gB1 + 4);
        gA0 += 32; gA1 += 32; gB0 += 32; gB1 += 32;
        __syncthreads();
        uint4 r;
        r.x = pack2(a00.x, a00.y); r.y = pack2(a00.z, a00.w);
        r.z = pack2(a01.x, a01.y); r.w = pack2(a01.z, a01.w);
        *(uint4*)lA0 = r;
        r.x = pack2(a10.x, a10.y); r.y = pack2(a10.z, a10.w);
        r.z = pack2(a11.x, a11.y); r.w = pack2(a11.z, a11.w);
        *(uint4*)lA1 = r;
        r.x = pack2(b00.x, b00.y); r.y = pack2(b00.z, b00.w);
        r.z = pack2(b01.x, b01.y); r.w = pack2(b01.z, b01.w);
        *(uint4*)lB0 = r;
        r.x = pack2(b10.x, b10.y); r.y = pack2(b10.z, b10.w);
        r.z = pack2(b11.x, b11.y); r.w = pack2(b11.z, b11.w);
        *(uint4*)lB1 = r;
        __syncthreads();
        s16x8 af[4], bfr[4];
#pragma unroll
        for (int mi = 0; mi < 4; mi++) af[mi]  = *(const s16x8*)(fA + mi * 16 * 32);
#pragma unroll
        for (int ni = 0; ni < 4; ni++) bfr[ni] = *(const s16x8*)(fB + ni * 16 * 32);
#pragma unroll
        for (int mi = 0; mi < 4; mi++)
#pragma unroll
            for (int ni = 0; ni < 4; ni++)
                acc[mi][ni] = __builtin_amdgcn_mfma_f32_16x16x32_bf16(
                    af[mi], bfr[ni], acc[mi][ni], 0, 0, 0);
    }

#pragma unroll
    for (int ni = 0; ni < 4; ni++) {
        const int col = bn + wc * 64 + ni * 16 + lane15;
#pragma unroll
        for (int mi = 0; mi < 4; mi++) {
#pragma unroll
            for (int r = 0; r < 4; r++) {
                const int m = wr * 64 + mi * 16 + lhi * 4 + r;
                atomicAdd(&C[(size_t)m * 1024 + col], acc[mi][ni][r]);
            }
        }
    }
}

// ---------------- causal depthwise conv1d (DC=5) + SiLU -> bf16 (bf16 in) ----------------
__global__ __launch_bounds__(256) void conv_silu_kernel(const u16* __restrict__ xz,
                                                        const float* __restrict__ cw,
                                                        const float* __restrict__ cb,
                                                        u16* __restrict__ uc)
{
    const int idx = blockIdx.x * 256 + threadIdx.x;   // over B*L*DI
    const int d  = idx & (DI_ - 1);
    const int bl = idx >> 11;
    const int l  = bl % L_;
    const int b  = bl / L_;
    const u16* u = xz + (size_t)b * L_ * (2 * DI_) + d;
    float acc = cb[d];
#pragma unroll
    for (int k = 0; k < DC_; k++) {
        const int ll = l + k - (DC_ - 1);
        if (ll >= 0) acc = fmaf(b2f(u[(size_t)ll * (2 * DI_)]), cw[d * DC_ + k], acc);
    }
    uc[(size_t)bl * DI_ + d] = f2b(silu_f(acc));
}

// ---------------- extract xdbl[:, 0:64] -> bf16 (dt_proj A operand) ----------------
__global__ __launch_bounds__(256) void dtext_kernel(const float* __restrict__ xdbl,
                                                    u16* __restrict__ dtb)
{
    const int idx = blockIdx.x * 256 + threadIdx.x;   // over ROWS*16
    const int row = idx >> 4, c4 = (idx & 15) * 4;
    float4 v = *(const float4*)(xdbl + (size_t)row * 96 + c4);
    uint2 r;
    r.x = pack2(v.x, v.y); r.y = pack2(v.z, v.w);
    *(uint2*)(dtb + (size_t)row * 64 + c4) = r;
}

// ---------------- selective scan: one thread per (b, d), DS=16 states in regs ----------------
__global__ __launch_bounds__(256) void scan_kernel(const u16* __restrict__ dt,
                                                   const u16* __restrict__ uc,
                                                   const u16* __restrict__ xz,
                                                   const float* __restrict__ xdbl,
                                                   const float* __restrict__ A_log,
                                                   const float* __restrict__ D_ssm,
                                                   u16* __restrict__ y)
{
    const int idx = blockIdx.x * 256 + threadIdx.x;   // over B*DI
    const int d = idx & (DI_ - 1);
    const int b = idx >> 11;
    float A[DS_];
#pragma unroll
    for (int s = 0; s < DS_; s++) A[s] = -__expf(A_log[d * DS_ + s]);
    const float Dv = D_ssm[d];
    float h[DS_] = {};
    for (int l = 0; l < L_; l++) {
        const size_t bl = (size_t)b * L_ + l;
        const float dtv = b2f(dt[bl * DI_ + d]);
        const float uv  = b2f(uc[bl * DI_ + d]);
        const float zv  = b2f(xz[bl * (2 * DI_) + DI_ + d]);
        const float* Bp = xdbl + bl * (DTR_ + 2 * DS_) + DTR_;
        const float* Cp = Bp + DS_;
        float yv = 0.f;
#pragma unroll
        for (int s = 0; s < DS_; s++) {
            h[s] = fmaf(h[s], __expf(dtv * A[s]), dtv * Bp[s] * uv);
            yv = fmaf(h[s], Cp[s], yv);
        }
        yv = fmaf(uv, Dv, yv);
        yv *= silu_f(zv);
        y[bl * DI_ + d] = f2b(yv);
    }
}

// ---------------- classifier layer 2 ----------------
__global__ __launch_bounds__(256) void cls2_kernel(const float* __restrict__ c,
                                                   const float* __restrict__ b1,
                                                   const float* __restrict__ W2,
                                                   const float* __restrict__ b2,
                                                   float* __restrict__ out)
{
    const int b = blockIdx.x;
    float s = 0.f;
    for (int n = threadIdx.x; n < D_; n += 256) {
        float v = c[b * D_ + n] + b1[n];
        v = silu_f(v);
        s = fmaf(v, W2[n], s);
    }
#pragma unroll
    for (int o = 32; o > 0; o >>= 1) s += __shfl_down(s, o, 64);
    __shared__ float red[4];
    const int wid = threadIdx.x >> 6;
    if ((threadIdx.x & 63) == 0) red[wid] = s;
    __syncthreads();
    if (threadIdx.x == 0) out[b] = red[0] + red[1] + red[2] + red[3] + b2[0];
}

extern "C" void kernel_launch(void* const* d_in, const int* in_sizes, int n_in,
                              void* d_out, int out_size, void* d_ws, size_t ws_size,
                              hipStream_t stream)
{
    const float* x         = (const float*)d_in[0];
    const float* n1w       = (const float*)d_in[1];
    const float* n1b       = (const float*)d_in[2];
    const float* in_projW  = (const float*)d_in[3];
    const float* conv_w    = (const float*)d_in[4];
    const float* conv_b    = (const float*)d_in[5];
    const float* x_projW   = (const float*)d_in[6];
    const float* dt_projW  = (const float*)d_in[7];
    const float* dt_projb  = (const float*)d_in[8];
    const float* A_log     = (const float*)d_in[9];
    const float* D_ssm     = (const float*)d_in[10];
    const float* out_projW = (const float*)d_in[11];
    const float* n2w       = (const float*)d_in[12];
    const float* n2b       = (const float*)d_in[13];
    const float* ffn_W1    = (const float*)d_in[14];
    const float* ffn_b1    = (const float*)d_in[15];
    const float* ffn_W2    = (const float*)d_in[16];
    const float* ffn_b2    = (const float*)d_in[17];
    const float* cls_W1    = (const float*)d_in[18];
    const float* cls_b1    = (const float*)d_in[19];
    const float* cls_W2    = (const float*)d_in[20];
    const float* cls_b2    = (const float*)d_in[21];

    // ---- workspace layout ----
    float* ws   = (float*)d_ws;
    u16*   xz_b = (u16*)ws;                            // ROWS*4096 u16
    u16*   uc_b = xz_b + (size_t)ROWS * 4096;          // ROWS*2048
    u16*   dt_b = uc_b + (size_t)ROWS * 2048;          // ROWS*2048
    u16*   y_b  = dt_b + (size_t)ROWS * 2048;          // ROWS*2048
    u16*   h_b  = y_b + (size_t)ROWS * 2048;           // ROWS*1024
    float* x2   = (float*)(h_b + (size_t)ROWS * 1024); // ROWS*1024 f32
    float* xdbl = x2 + (size_t)ROWS * 1024;            // ROWS*96 f32
    u16*   dtb  = (u16*)(xdbl + (size_t)ROWS * 96);    // ROWS*64 u16
    u16*   wbuf = dtb + (size_t)ROWS * 64;             // WTOT u16
    float* clsh = (float*)(wbuf + (size_t)WTOT);       // 128*1024 f32
    float* pq   = clsh + (size_t)B_ * D_;              // 2 * ROWS*1024 f32 (split-K partials)

    float* outv = (float*)d_out;    // (B,1)
    float* x3   = outv + B_;        // (B,L,D)

    // 0. all weight conversions (independent of activations)
    f2b_all_kernel<<<dim3(5312), dim3(256), 0, stream>>>(
        in_projW, out_projW, ffn_W1, ffn_W2, x_projW, dt_projW, wbuf);
    // 1. LN1 -> bf16
    ln_kernel<<<dim3(ROWS), dim3(256), 0, stream>>>(x, n1w, n1b, h_b);
    // 2. in_proj (MFMA) -> bf16 xz   (3968 x 4096, K=1024)
    gemm_mfma<0, false, false, 1><<<dim3(32, 31, 1), dim3(256), 0, stream>>>(
        h_b, wbuf + W_IN, nullptr, nullptr, xz_b, ROWS, D_, 2 * DI_, D_);
    // 3. causal conv + SiLU -> bf16
    conv_silu_kernel<<<dim3(ROWS * DI_ / 256), dim3(256), 0, stream>>>(xz_b, conv_w, conv_b, uc_b);
    // 4. x_proj (split-K x16 MFMA, atomic f32): xdbl = uc @ x_proj_W^T   (3968 x 96, K=2048)
    hipMemsetAsync(xdbl, 0, (size_t)ROWS * 96 * sizeof(float), stream);
    gemm_mfma<0, false, false, 2><<<dim3(1, 31, 16), dim3(256), 0, stream>>>(
        uc_b, wbuf + W_XP, nullptr, nullptr, xdbl, ROWS, DI_, DTR_ + 2 * DS_, 128);
    // 5. dt_proj (MFMA, softplus) -> bf16   (3968 x 2048, K=64)
    dtext_kernel<<<dim3(ROWS * 16 / 256), dim3(256), 0, stream>>>(xdbl, dtb);
    gemm_mfma<2, true, false, 1><<<dim3(16, 31, 1), dim3(256), 0, stream>>>(
        dtb, wbuf + W_DT, dt_projb, nullptr, dt_b, ROWS, DTR_, DI_, DTR_);
    // 6. selective scan (+ skip + gate) -> bf16 y
    scan_kernel<<<dim3(B_ * DI_ / 256), dim3(256), 0, stream>>>(
        dt_b, uc_b, xz_b, xdbl, A_log, D_ssm, y_b);
    // 7. out_proj split-K z=2 -> partials p0,p1   (3968 x 1024, K=2048)
    gemm_mfma<0, false, false, 3><<<dim3(8, 31, 2), dim3(256), 0, stream>>>(
        y_b, wbuf + W_OUT, nullptr, nullptr, pq, ROWS, DI_, D_, 1024);
    // 8. fused combine + LN2: x2 = x + p0 + p1 (f32), h2 = LN(x2) -> bf16
    ln2_fuse_kernel<<<dim3(ROWS), dim3(256), 0, stream>>>(
        x, pq, pq + (size_t)ROWS * D_, n2w, n2b, x2, h_b);
    // 9. ffn1 (MFMA) + bias + SiLU -> bf16   (3968 x 2048, K=1024)
    gemm_mfma<1, true, false, 1><<<dim3(16, 31, 1), dim3(256), 0, stream>>>(
        h_b, wbuf + W_F1, ffn_b1, nullptr, uc_b, ROWS, D_, 2 * D_, D_);
    // 10. ffn2 split-K z=2 -> partials q0,q1   (3968 x 1024, K=2048)
    gemm_mfma<0, false, false, 3><<<dim3(8, 31, 2), dim3(256), 0, stream>>>(
        uc_b, wbuf + W_F2, nullptr, nullptr, pq, ROWS, 2 * D_, D_, 1024);
    // 11. combine: x3 = x2 + q0 + q1 + b2 -> d_out
    add3_bias_kernel<<<dim3(ROWS * D_ / 4 / 256), dim3(256), 0, stream>>>(
        x2, pq, pq + (size_t)ROWS * D_, ffn_b2, x3);
    // 12. classifier layer 1: split-K MFMA, fused f32->bf16 staging
    hipMemsetAsync(clsh, 0, (size_t)B_ * D_ * sizeof(float), stream);
    gemm_cls_mfma<<<dim3(1024 / 128, KCLS / KCH), dim3(256), 0, stream>>>(x3, cls_W1, clsh);
    // 13. classifier layer 2
    cls2_kernel<<<dim3(B_), dim3(256), 0, stream>>>(clsh, cls_b1, cls_W2, cls_b2, outv);
}